// Round 8
// baseline (470.840 us; speedup 1.0000x reference)
//
#include <hip/hip_runtime.h>

// ---------------- constants ----------------
#define S      4096
#define DM     1024
#define NB     4
#define NH     16
#define HDIM   64
#define MTOT   (NB * S)          // 16384
#define DS     ((long)DM * S)    // 4,194,304
#define MH     2304              // padded half-rows for Mc2 (2049 used)
#define KH     2112              // folded K for Mc2 (2049 used)
#define KH2    2112              // folded K for even/odd G split (2049 used)
#define MEO    2048              // even/odd GEMM rows (n=0..2047; n=2048 special)

typedef __attribute__((ext_vector_type(8))) short short8;
typedef __attribute__((ext_vector_type(4))) float f32x4;
typedef __attribute__((ext_vector_type(8))) unsigned short u16x8;
typedef __attribute__((ext_vector_type(4))) unsigned short u16x4;

__device__ __forceinline__ unsigned short f2bf(float f) {
  union { float f; unsigned u; } v; v.f = f;
  unsigned r = v.u + 0x7fffu + ((v.u >> 16) & 1u);   // RNE
  return (unsigned short)(r >> 16);
}
__device__ __forceinline__ float bf2f(short h) {
  union { unsigned u; float f; } v; v.u = ((unsigned)(unsigned short)h) << 16;
  return v.f;
}

#define GLOAD(gp, lp) __builtin_amdgcn_global_load_lds( \
    (const __attribute__((address_space(1))) void*)(gp), \
    (__attribute__((address_space(3))) void*)(lp), 16, 0, 0)

#define SBAR() do { asm volatile("" ::: "memory"); __builtin_amdgcn_s_barrier(); \
                    asm volatile("" ::: "memory"); } while (0)
#define WAITL0() asm volatile("s_waitcnt lgkmcnt(0)" ::: "memory")

// LDS swizzle for 64B-row tiles: XOR byte bits 4-5 with row bits 1-2 (byte bits 7-8).
#define SWZ(o) ((o) ^ ((((o) >> 7) & 3) << 4))

// ---------------- small kernels ----------------

__global__ void k_tables(const float* __restrict__ fd, const float* __restrict__ alpha,
                         const float* __restrict__ fsc,
                         float* __restrict__ cos_tab, float* __restrict__ c_arr) {
  int k = blockIdx.x * 256 + threadIdx.x;
  if (k >= S) return;
  float aa = alpha[0] + fsc[0] * (fd[0] - 1.5f);
  const float twopi = 6.28318530717958647692f;
  cos_tab[k] = cosf(twopi * ((float)k / (float)S));
  int kk = (k <= S / 2) ? k : (S - k);
  float af = (float)kk / (float)S;
  c_arr[k] = cosf(aa * atanf(logf(af + 1e-10f)));
}

// g[j] = (1/S) sum_k c[k] cos(2 pi j k / S); 16 lanes per j, deterministic reduce
__global__ void k_g(const float* __restrict__ cos_tab, const float* __restrict__ c_arr,
                    float* __restrict__ g) {
  __shared__ float sct[S];
  __shared__ float sc[S];
  __shared__ float red[16][17];
  for (int i = threadIdx.x; i < S; i += 256) { sct[i] = cos_tab[i]; sc[i] = c_arr[i]; }
  __syncthreads();
  int jl = threadIdx.x >> 4, r = threadIdx.x & 15;
  int j = blockIdx.x * 16 + jl;
  float acc = 0.f;
#pragma unroll 4
  for (int i = 0; i < 256; ++i) {
    int k = r + 16 * i;
    acc += sc[k] * sct[(j * k) & (S - 1)];
  }
  red[jl][r] = acc;
  __syncthreads();
  if (r == 0) {
    float s = 0.f;
#pragma unroll
    for (int i = 0; i < 16; ++i) s += red[jl][i];
    g[j] = s * (1.f / (float)S);
  }
}

// Ge/Go [MEO][KH2] bf16, Go at offset MEO*KH2.
__global__ void k_buildEO(const float* __restrict__ g, short* __restrict__ Ge) {
  long i8 = ((long)blockIdx.x * 256 + threadIdx.x) * 8;
  if (i8 >= (long)MEO * KH2) return;
  int n = (int)(i8 / KH2);
  int m = (int)(i8 % KH2);
  u16x8 ev, ov;
#pragma unroll
  for (int j = 0; j < 8; ++j) {
    int mm = m + j;
    float e, o;
    if (mm == 0)            { e = g[n]; o = 0.f; }
    else if (mm == 2048)    { e = g[(n + 2048) & (S - 1)]; o = 0.f; }
    else if (mm > 2048)     { e = 0.f; o = 0.f; }
    else {
      float a = g[(n - mm) & (S - 1)], b = g[(n + mm) & (S - 1)];
      e = 0.5f * (a + b); o = 0.5f * (a - b);
    }
    ev[j] = f2bf(e); ov[j] = f2bf(o);
  }
  *(u16x8*)(Ge + i8) = ev;
  *(u16x8*)(Ge + (long)MEO * KH2 + i8) = ov;
}

// fold x into u,v (transposed): uv[b][d][m] = x[b][m][d] +/- x[b][4096-m][d]
__global__ void k_foldT(const float* __restrict__ x, short* __restrict__ uv) {
  __shared__ float tp[64][65];
  __shared__ float tm[64][65];
  int m0 = blockIdx.x * 64, d0 = blockIdx.y * 64, b = blockIdx.z;
  int t = threadIdx.x;
  int r = t >> 4, c4 = (t & 15) * 4;
#pragma unroll
  for (int rr = 0; rr < 4; ++rr) {
    int m = m0 + r + rr * 16;
    float4 vp = *(const float4*)(x + ((long)(b * S + m)) * DM + d0 + c4);
    int ms = (S - m) & (S - 1);
    float4 vm = *(const float4*)(x + ((long)(b * S + ms)) * DM + d0 + c4);
    tp[r + rr * 16][c4 + 0] = vp.x; tp[r + rr * 16][c4 + 1] = vp.y;
    tp[r + rr * 16][c4 + 2] = vp.z; tp[r + rr * 16][c4 + 3] = vp.w;
    tm[r + rr * 16][c4 + 0] = vm.x; tm[r + rr * 16][c4 + 1] = vm.y;
    tm[r + rr * 16][c4 + 2] = vm.z; tm[r + rr * 16][c4 + 3] = vm.w;
  }
  __syncthreads();
  int m_loc = t & 63, dq = t >> 6;
#pragma unroll
  for (int i = 0; i < 16; ++i) {
    int d_loc = dq * 16 + i;
    int m = m0 + m_loc;
    float P = tp[m_loc][d_loc], M = tm[m_loc][d_loc];
    float u, v;
    if (m == 0 || m == 2048) { u = P; v = 0.f; }
    else if (m > 2048)       { u = 0.f; v = 0.f; }
    else                     { u = P + M; v = P - M; }
    long base = ((long)(b * DM + d0 + d_loc)) * KH2 + m;
    uv[base] = (short)f2bf(u);
    uv[base + (long)4 * DM * KH2] = (short)f2bf(v);
  }
}

// Xs[b][2048][d] = sum_m g[2048-m] * u[b][d][m]; one block per (b,d), LDS tree-reduce
__global__ void k_row2048(const float* __restrict__ g, const short* __restrict__ uv,
                          short* __restrict__ Xs) {
  __shared__ float red[256];
  int bd = blockIdx.x;                 // 0..NB*DM-1
  int b = bd >> 10, d = bd & (DM - 1);
  const short* up = uv + ((long)(b * DM + d)) * KH2;
  int t = threadIdx.x;
  float acc = 0.f;
  for (int m = t; m <= 2048; m += 256)
    acc += g[2048 - m] * bf2f(up[m]);
  red[t] = acc;
  __syncthreads();
  for (int sh = 128; sh > 0; sh >>= 1) {
    if (t < sh) red[t] += red[t + sh];
    __syncthreads();
  }
  if (t == 0) Xs[((long)b * S + 2048) * DM + d] = (short)f2bf(red[0]);
}

// unfold: Xs[b][n] = A[n]+B[n]; Xs[b][4096-n] = A[n]-B[n] (n>0). AB=[8][MEO][DM]
__global__ void k_unfold(const short* __restrict__ AB, short* __restrict__ Xs) {
  long i8 = ((long)blockIdx.x * 256 + threadIdx.x) * 8;
  if (i8 >= (long)NB * MEO * DM) return;
  int b = (int)(i8 >> 21);             // MEO*DM = 2^21
  long rr = i8 & ((1L << 21) - 1);
  int n = (int)(rr >> 10);
  int d = (int)(rr & (DM - 1));
  u16x8 av = *(const u16x8*)(AB + i8);
  u16x8 bv = *(const u16x8*)(AB + ((long)4 * MEO * DM) + i8);
  u16x8 sv, dv;
#pragma unroll
  for (int j = 0; j < 8; ++j) {
    float A = bf2f((short)av[j]), B = bf2f((short)bv[j]);
    sv[j] = f2bf(A + B);
    dv[j] = f2bf(A - B);
  }
  *(u16x8*)(Xs + ((long)b * S + n) * DM + d) = sv;
  if (n > 0)
    *(u16x8*)(Xs + ((long)b * S + (S - n)) * DM + d) = dv;
}

// Mc2[n][m] (n<MH, m<KH, ld KH): (m<=2048) ? cos(2*pi*n*m/S)/64 : 0
__global__ void k_buildM2(const float* __restrict__ cos_tab, short* __restrict__ Mc2) {
  long i8 = ((long)blockIdx.x * 256 + threadIdx.x) * 8;
  if (i8 >= (long)MH * KH) return;
  int n = (int)(i8 / KH);
  int m = (int)(i8 % KH);
  u16x8 mv;
#pragma unroll
  for (int j = 0; j < 8; ++j) {
    int mm = m + j;
    float vv = (mm <= 2048) ? cos_tab[(n * mm) & (S - 1)] * 0.015625f : 0.f;
    mv[j] = f2bf(vv);
  }
  *(u16x8*)(Mc2 + i8) = mv;
}

// W [K][N] fp32 -> WT [N][K] bf16, tiled coalesced transpose
__global__ void k_transW(const float* __restrict__ W, short* __restrict__ WT) {
  __shared__ float tile[64][65];
  int k0 = blockIdx.x * 64, n0 = blockIdx.y * 64;
  int t = threadIdx.x;
  int r = t >> 4, c4 = (t & 15) * 4;
  const float* ip = W + (long)k0 * DM + n0;
#pragma unroll
  for (int rr = 0; rr < 4; ++rr) {
    float4 v = *(const float4*)(ip + (long)(r + rr * 16) * DM + c4);
    tile[r + rr * 16][c4 + 0] = v.x;
    tile[r + rr * 16][c4 + 1] = v.y;
    tile[r + rr * 16][c4 + 2] = v.z;
    tile[r + rr * 16][c4 + 3] = v.w;
  }
  __syncthreads();
  int k_loc = t & 63, nq = t >> 6;
  short* op = WT + (long)n0 * DM + k0;
#pragma unroll
  for (int i = 0; i < 16; ++i) {
    int n_loc = nq * 16 + i;
    op[(long)n_loc * DM + k_loc] = (short)f2bf(tile[k_loc][n_loc]);
  }
}

__global__ void k_logits(const short* __restrict__ Qt, const short* __restrict__ Kt,
                         float* __restrict__ logits) {
  int s = blockIdx.x * 256 + threadIdx.x;
  int h = blockIdx.y, b = blockIdx.z;
  const short* q = Qt + ((long)b * DM + h * HDIM) * S + s;
  const short* k = Kt + ((long)b * DM + h * HDIM) * S + s;
  float acc = 0.f;
#pragma unroll 8
  for (int j = 0; j < HDIM; ++j)
    acc += bf2f(q[(long)j * S]) * bf2f(k[(long)j * S]);
  logits[((long)b * NH + h) * S + s] = acc * 0.125f;
}

__global__ void k_softw(const float* __restrict__ logits, float* __restrict__ w) {
  int idx = blockIdx.x * 256 + threadIdx.x;
  if (idx >= NB * S) return;
  int b = idx >> 12, s = idx & (S - 1);
  const float* lp = logits + (long)b * NH * S + s;
  float v[NH];
  float m = -1e30f;
#pragma unroll
  for (int h = 0; h < NH; ++h) { v[h] = lp[(long)h * S]; m = fmaxf(m, v[h]); }
  float sum = 0.f;
#pragma unroll
  for (int h = 0; h < NH; ++h) { v[h] = expf(v[h] - m); sum += v[h]; }
  float inv = 1.f / sum;
  float* wp = w + (long)b * NH * S + s;
#pragma unroll
  for (int h = 0; h < NH; ++h) wp[(long)h * S] = v[h] * inv;
}

__global__ void k_att(short* vt, const float* __restrict__ wsm) {
  long i8 = ((long)blockIdx.x * 256 + threadIdx.x) * 8;
  if (i8 >= (long)NB * DS) return;
  int b = (int)(i8 >> 22);
  long r = i8 & (DS - 1);
  int d = (int)(r >> 12);
  int s = (int)(r & (S - 1));
  int h = d >> 6;
  const float* wp = wsm + ((long)b * NH + h) * S + s;
  u16x8 vv = *(const u16x8*)(vt + i8);
  u16x8 ov;
#pragma unroll
  for (int j = 0; j < 8; ++j) ov[j] = f2bf(wp[j] * bf2f((short)vv[j]));
  *(u16x8*)(vt + i8) = ov;
}

// A2t[b][d][m] (ld KH): exact column-fold of the ifft cos matrix
__global__ void k_fold(const short* __restrict__ att, short* __restrict__ A2t) {
  int m = blockIdx.x * 256 + threadIdx.x;
  if (m >= KH) return;
  int d = blockIdx.y, b = blockIdx.z;
  const short* ap = att + ((long)b * DM + d) * S;
  float v;
  if (m == 0) v = bf2f(ap[0]);
  else if (m < 2048) v = bf2f(ap[m]) + bf2f(ap[4096 - m]);
  else if (m == 2048) v = bf2f(ap[2048]);
  else v = 0.f;
  A2t[((long)b * DM + d) * KH + m] = (short)f2bf(v);
}

// ---------------- 256x256 8-phase GEMM ----------------
// C = A @ B ; A row-major [M,K] bf16, B TRANSPOSED as Bt [N,K] bf16, ld = K.
// AMIR: A rows via even-symmetry mirror (att_time_half).
// ASEL: A base = A + (bz>>2)*aBatch (even/odd matrix pair), B/C batched by bz.
// EPI 0: bf16 C[M,N] per-batch.
// EPI 1 (C^T orientation): rows = dout in [0,3072), cols = flattened (b,s).
//        Writes bf16 into [b][dout&1023][s] of Cb/Cb2/Cb3 by dout>>10, + bias*bsc.
// EPI 2: fp32 C + bias + resid.
template <int EPI, int AMIR = 0, int ASEL = 0>
__global__ __launch_bounds__(512, 2) void gemm8(
    const short* __restrict__ A, const short* __restrict__ Bt,
    short* __restrict__ Cb, short* __restrict__ Cb2, short* __restrict__ Cb3,
    float* __restrict__ Cf,
    const float* __restrict__ bias, const float* __restrict__ bias2,
    const float* __restrict__ bias3,
    const float* __restrict__ bsc, const float* __restrict__ resid,
    int M, int N, int K, long aBatch, long bBatch, long cBatch) {
  __shared__ __align__(16) short As[2][2][256 * 32];   // 64 KiB
  __shared__ __align__(16) short Bs[2][2][256 * 32];   // 64 KiB

  // bijective XCD-chunked remap (nwg % 8 == 0 in all our launches)
  const int gx = gridDim.x, gy = gridDim.y;
  const int nwg = gx * gy * gridDim.z;
  int lin = blockIdx.x + gx * (blockIdx.y + gy * blockIdx.z);
  int wg = lin;
  if ((nwg & 7) == 0) {
    const int cpx = nwg >> 3;
    wg = (lin & 7) * cpx + (lin >> 3);
  }
  const int NTN = N >> 8;
  const int ntile = wg % NTN;
  const int rest = wg / NTN;
  const int NTM = M >> 8;
  const int mtile = rest % NTM;
  const int bz = rest / NTM;

  const short* Ag = ASEL ? (A + (long)(bz >> 2) * aBatch) : (A + (long)bz * aBatch);
  const short* Bg = Bt + (long)bz * bBatch;
  const int m0 = mtile << 8, n0 = ntile << 8;
  const int tid = threadIdx.x;
  const int lane = tid & 63;
  const int wid = tid >> 6;
  const int wm = wid >> 2, wn = wid & 3;

  f32x4 acc[8][4];
#pragma unroll
  for (int i = 0; i < 8; ++i)
#pragma unroll
    for (int j = 0; j < 4; ++j) acc[i][j] = (f32x4){0.f, 0.f, 0.f, 0.f};

  const int NT = K >> 6;
  auto stage = [&](int h) {
    const int tau = h >> 2, q = h & 3;
    const int buf = tau & 1, ks = q >> 1;
    short* ldsbase = (q & 1) ? &Bs[buf][ks][0] : &As[buf][ks][0];
    const short* gsrc = (q & 1) ? Bg : Ag;
    const int row0 = (q & 1) ? n0 : m0;
    const long k0 = (long)tau * 64 + ks * 32;
#pragma unroll
    for (int j = 0; j < 2; ++j) {
      const int o = tid * 16 + j * 8192;
      const int lo = SWZ(o);
      const int row = lo >> 6;
      const int cs = (lo & 63) >> 1;
      const short* gp;
      if (AMIR && !(q & 1)) {
        int grow = row0 + row;
        int b_ = grow >> 12, s_ = grow & (S - 1);
        int sm = (s_ <= 2048) ? s_ : (4096 - s_);
        gp = Ag + ((long)b_ * MH + sm) * K + k0 + cs;
      } else {
        gp = gsrc + (long)(row0 + row) * K + k0 + cs;
      }
      GLOAD(gp, (short*)((char*)ldsbase + o));
    }
  };

  for (int h = 0; h < 7; ++h) stage(h);
  asm volatile("s_waitcnt vmcnt(6)" ::: "memory");
  SBAR();

  short8 bf[4];
  for (int t = 0; t < NT; ++t) {
    const int buf = t & 1;
#pragma unroll
    for (int p = 0; p < 4; ++p) {
      const int ks = p >> 1, mh = p & 1;
      short8 af[4];
      {
        const short* Ah = &As[buf][ks][0];
        const int kb = (lane >> 4) * 16;
        const int r0 = wm * 128 + mh * 64 + (lane & 15);
#pragma unroll
        for (int i = 0; i < 4; ++i) {
          int byte = (r0 + i * 16) * 64 + kb;
          byte = SWZ(byte);
          af[i] = *(const short8*)((const char*)Ah + byte);
        }
        if (mh == 0) {
          const short* Bh = &Bs[buf][ks][0];
          const int c0 = wn * 64 + (lane & 15);
#pragma unroll
          for (int j = 0; j < 4; ++j) {
            int byte = (c0 + j * 16) * 64 + kb;
            byte = SWZ(byte);
            bf[j] = *(const short8*)((const char*)Bh + byte);
          }
        }
      }
      { const int h = 4 * t + p + 7; if (h < 4 * NT) stage(h); }
      SBAR();
      WAITL0();
      __builtin_amdgcn_s_setprio(1);
#pragma unroll
      for (int i = 0; i < 4; ++i)
#pragma unroll
        for (int j = 0; j < 4; ++j)
          acc[mh * 4 + i][j] = __builtin_amdgcn_mfma_f32_16x16x32_bf16(
              af[i], bf[j], acc[mh * 4 + i][j], 0, 0, 0);
      __builtin_amdgcn_s_setprio(0);
      if (p == 3) {
        if (t < NT - 2) {
          asm volatile("s_waitcnt vmcnt(6)" ::: "memory");
        } else if (t == NT - 2) {
          asm volatile("s_waitcnt vmcnt(0)" ::: "memory");
        }
      }
      SBAR();
    }
  }

  // epilogue: C/D layout col = lane&15, row = (lane>>4)*4 + reg
  const int rl = (lane >> 4) << 2;
#pragma unroll
  for (int f = 0; f < 8; ++f) {
    const int rbase = m0 + wm * 128 + f * 16 + rl;
#pragma unroll
    for (int j = 0; j < 4; ++j) {
      const int col = n0 + wn * 64 + j * 16 + (lane & 15);
      f32x4 a = acc[f][j];
      if constexpr (EPI == 0) {
        short* cp = Cb + (long)bz * cBatch;
#pragma unroll
        for (int r = 0; r < 4; ++r)
          cp[(long)(rbase + r) * N + col] = (short)f2bf(a[r]);
      } else if constexpr (EPI == 1) {
        // rows = dout, cols = (b,s): coalesced write along s
        const float sc = bsc ? bsc[0] : 1.f;
        const int b_ = col >> 12;
        const int s_ = col & (S - 1);
#pragma unroll
        for (int r = 0; r < 4; ++r) {
          const int row = rbase + r;
          const int pidx = row >> 10;
          const int d = row & (DM - 1);
          short* Cp = (pidx == 0) ? Cb : ((pidx == 1) ? Cb2 : Cb3);
          const float* bp = (pidx == 0) ? bias : ((pidx == 1) ? bias2 : bias3);
          const float bi = bp ? bp[d] * sc : 0.f;
          Cp[((long)(b_ * DM + d)) * S + s_] = (short)f2bf(a[r] + bi);
        }
      } else {
        float bi = bias[col];
#pragma unroll
        for (int r = 0; r < 4; ++r) {
          long o = (long)(rbase + r) * N + col;
          Cf[o] = a[r] + bi + resid[o];
        }
      }
    }
  }
}

// ---------------- launch ----------------
extern "C" void kernel_launch(void* const* d_in, const int* in_sizes, int n_in,
                              void* d_out, int out_size, void* d_ws, size_t ws_size,
                              hipStream_t stream) {
  const float* x     = (const float*)d_in[0];
  const float* fd    = (const float*)d_in[1];
  const float* Wq    = (const float*)d_in[2];
  const float* bq    = (const float*)d_in[3];
  const float* Wk    = (const float*)d_in[4];
  const float* bk    = (const float*)d_in[5];
  const float* Wv    = (const float*)d_in[6];
  const float* bv    = (const float*)d_in[7];
  const float* Wo    = (const float*)d_in[8];
  const float* bo    = (const float*)d_in[9];
  const float* alpha = (const float*)d_in[10];
  const float* fsc   = (const float*)d_in[11];
  float* out = (float*)d_out;

  // --- workspace layout (~110 MB) ---
  char* wp = (char*)d_ws;
  auto alloc = [&](size_t bytes) {
    char* p = wp;
    wp += (bytes + 255) & ~(size_t)255;
    return p;
  };
  float* cos_tab = (float*)alloc(S * 4);
  float* c_arr   = (float*)alloc(S * 4);          // c_arr[0] = c0 bias factor
  float* g       = (float*)alloc(S * 4);
  float* logits  = (float*)alloc((size_t)NB * NH * S * 4);
  float* wsm     = (float*)alloc((size_t)NB * NH * S * 4);
  short* WTcat = (short*)alloc((size_t)3 * DM * DM * 2);  // [3072][1024]
  short* WoT   = (short*)alloc((size_t)DM * DM * 2);
  short* slotA = (short*)alloc((size_t)NB * DS * 2);  // ABout -> VtT
  short* slotB = (short*)alloc((size_t)NB * DS * 2);  // Ge/Go -> Mc2 + A2t
  short* slotC = (short*)alloc((size_t)NB * DS * 2);  // Xs -> att_half

  // d_out scratch phases: uv (34.6MB) during G-phase; QtT/KtT during attention
  short* uv  = (short*)d_out;                       // [8][DM][KH2]
  short* QtT = (short*)d_out;
  short* KtT = (short*)d_out + (size_t)2 * DS;

  short* Ge  = slotB;                               // [2][MEO][KH2] (Ge,Go)
  short* ABout = slotA;                             // [8][MEO][DM]
  short* Xs  = slotC;
  short* VtT = slotA;
  short* Mc2 = slotB;                               // 9.73 MB
  short* A2t = (short*)((char*)slotB + 10u * 1024 * 1024);
  short* att_half = slotC;

  dim3 blk(256), blk8(512);

  // tables, filter, even/odd matrices, fold
  k_tables<<<dim3(S / 256), blk, 0, stream>>>(fd, alpha, fsc, cos_tab, c_arr);
  k_g<<<dim3(S / 16), blk, 0, stream>>>(cos_tab, c_arr, g);
  k_buildEO<<<dim3((unsigned)((long)MEO * KH2 / 8 / 256)), blk, 0, stream>>>(g, Ge);
  k_foldT<<<dim3(33, DM / 64, NB), blk, 0, stream>>>(x, uv);

  // weight transposes
  k_transW<<<dim3(16, 16), blk, 0, stream>>>(Wq, WTcat);
  k_transW<<<dim3(16, 16), blk, 0, stream>>>(Wk, WTcat + (size_t)DM * DM);
  k_transW<<<dim3(16, 16), blk, 0, stream>>>(Wv, WTcat + (size_t)2 * DM * DM);
  k_transW<<<dim3(16, 16), blk, 0, stream>>>(Wo, WoT);

  // even/odd spectral GEMM: AB[z] = (z<4 ? Ge : Go) @ uv[z]; 256 wg
  dim3 geo(DM / 256, MEO / 256, 8);
  gemm8<0, 0, 1><<<geo, blk8, 0, stream>>>(Ge, uv, ABout, nullptr, nullptr, nullptr,
                                           nullptr, nullptr, nullptr, nullptr, nullptr,
                                           MEO, DM, KH2,
                                           (long)MEO * KH2, (long)DM * KH2, (long)MEO * DM);
  // row n=2048 + unfold mirror into Xs [b][s][d]
  k_row2048<<<dim3(NB * DM), blk, 0, stream>>>(g, uv, Xs);
  k_unfold<<<dim3((unsigned)((long)NB * MEO * DM / 8 / 256)), blk, 0, stream>>>(ABout, Xs);

  // fused q/k/v projections, C^T orientation: C[dout][(b,s)] = WTcat @ Xs^T.
  // Bt = Xs ([s][d] row-major == Bt[N][K] with N=MTOT, K=DM). Coalesced writes.
  dim3 gqkv(MTOT / 256, 3 * DM / 256, 1);   // (64,12,1) = 768 wg
  gemm8<1><<<gqkv, blk8, 0, stream>>>(WTcat, Xs, QtT, KtT, VtT, nullptr,
                                      bq, bk, bv, c_arr, nullptr,
                                      3 * DM, MTOT, DM, 0, 0, 0);

  // logits, softmax over heads, attended (in-place on v_t)
  k_logits<<<dim3(S / 256, NH, NB), blk, 0, stream>>>(QtT, KtT, logits);
  k_softw<<<dim3(NB * S / 256), blk, 0, stream>>>(logits, wsm);
  k_att<<<dim3((unsigned)((long)NB * DS / 8 / 256)), blk, 0, stream>>>(VtT, wsm);

  // fold att (ifft even symmetry), half-cos matrix, att_time_half = Mc2 @ A2
  k_fold<<<dim3(KH / 256 + 1, DM, NB), blk, 0, stream>>>(VtT, A2t);
  k_buildM2<<<dim3((unsigned)((long)MH * KH / 8 / 256)), blk, 0, stream>>>(cos_tab, Mc2);
  dim3 ghalf(DM / 256, MH / 256, NB);
  gemm8<0><<<ghalf, blk8, 0, stream>>>(Mc2, A2t, att_half, nullptr, nullptr, nullptr,
                                       nullptr, nullptr, nullptr, nullptr, nullptr,
                                       MH, DM, KH, 0, (long)DM * KH, (long)MH * DM);

  // out = att_time @ Wo + bo + x  (A rows via mirror; fp32 epilogue)
  dim3 gproj(DM / 256, MTOT / 256, 1);
  gemm8<2, 1><<<gproj, blk8, 0, stream>>>(att_half, WoT, nullptr, nullptr, nullptr, out,
                                          bo, nullptr, nullptr, nullptr, x,
                                          MTOT, DM, DM, 0, 0, 0);
}

// Round 9
// 468.944 us; speedup vs baseline: 1.0040x; 1.0040x over previous
//
#include <hip/hip_runtime.h>

// ---------------- constants ----------------
#define S      4096
#define DM     1024
#define NB     4
#define NH     16
#define HDIM   64
#define MTOT   (NB * S)          // 16384
#define DS     ((long)DM * S)    // 4,194,304
#define MH     2304              // padded half-rows for Mc2 (2049 used)
#define KH     2112              // folded K for Mc2 (2049 used)
#define KH2    2112              // folded K for even/odd G split (2049 used)
#define MEO    2048              // even/odd GEMM rows (n=0..2047; n=2048 special)

typedef __attribute__((ext_vector_type(8))) short short8;
typedef __attribute__((ext_vector_type(4))) float f32x4;
typedef __attribute__((ext_vector_type(8))) unsigned short u16x8;
typedef __attribute__((ext_vector_type(4))) unsigned short u16x4;

__device__ __forceinline__ unsigned short f2bf(float f) {
  union { float f; unsigned u; } v; v.f = f;
  unsigned r = v.u + 0x7fffu + ((v.u >> 16) & 1u);   // RNE
  return (unsigned short)(r >> 16);
}
__device__ __forceinline__ float bf2f(short h) {
  union { unsigned u; float f; } v; v.u = ((unsigned)(unsigned short)h) << 16;
  return v.f;
}

#define GLOAD(gp, lp) __builtin_amdgcn_global_load_lds( \
    (const __attribute__((address_space(1))) void*)(gp), \
    (__attribute__((address_space(3))) void*)(lp), 16, 0, 0)

#define SBAR() do { asm volatile("" ::: "memory"); __builtin_amdgcn_s_barrier(); \
                    asm volatile("" ::: "memory"); } while (0)
#define WAITL0() asm volatile("s_waitcnt lgkmcnt(0)" ::: "memory")

// LDS swizzle for 64B-row tiles: XOR byte bits 4-5 with row bits 1-2 (byte bits 7-8).
#define SWZ(o) ((o) ^ ((((o) >> 7) & 3) << 4))

// ---------------- small kernels ----------------

__global__ void k_tables(const float* __restrict__ fd, const float* __restrict__ alpha,
                         const float* __restrict__ fsc,
                         float* __restrict__ cos_tab, float* __restrict__ c_arr) {
  int k = blockIdx.x * 256 + threadIdx.x;
  if (k >= S) return;
  float aa = alpha[0] + fsc[0] * (fd[0] - 1.5f);
  const float twopi = 6.28318530717958647692f;
  cos_tab[k] = cosf(twopi * ((float)k / (float)S));
  int kk = (k <= S / 2) ? k : (S - k);
  float af = (float)kk / (float)S;
  c_arr[k] = cosf(aa * atanf(logf(af + 1e-10f)));
}

// g[j] = (1/S) sum_k c[k] cos(2 pi j k / S); 16 lanes per j, deterministic reduce
__global__ void k_g(const float* __restrict__ cos_tab, const float* __restrict__ c_arr,
                    float* __restrict__ g) {
  __shared__ float sct[S];
  __shared__ float sc[S];
  __shared__ float red[16][17];
  for (int i = threadIdx.x; i < S; i += 256) { sct[i] = cos_tab[i]; sc[i] = c_arr[i]; }
  __syncthreads();
  int jl = threadIdx.x >> 4, r = threadIdx.x & 15;
  int j = blockIdx.x * 16 + jl;
  float acc = 0.f;
#pragma unroll 4
  for (int i = 0; i < 256; ++i) {
    int k = r + 16 * i;
    acc += sc[k] * sct[(j * k) & (S - 1)];
  }
  red[jl][r] = acc;
  __syncthreads();
  if (r == 0) {
    float s = 0.f;
#pragma unroll
    for (int i = 0; i < 16; ++i) s += red[jl][i];
    g[j] = s * (1.f / (float)S);
  }
}

// Ge/Go [MEO][KH2] bf16, Go at offset MEO*KH2.
__global__ void k_buildEO(const float* __restrict__ g, short* __restrict__ Ge) {
  long i8 = ((long)blockIdx.x * 256 + threadIdx.x) * 8;
  if (i8 >= (long)MEO * KH2) return;
  int n = (int)(i8 / KH2);
  int m = (int)(i8 % KH2);
  u16x8 ev, ov;
#pragma unroll
  for (int j = 0; j < 8; ++j) {
    int mm = m + j;
    float e, o;
    if (mm == 0)            { e = g[n]; o = 0.f; }
    else if (mm == 2048)    { e = g[(n + 2048) & (S - 1)]; o = 0.f; }
    else if (mm > 2048)     { e = 0.f; o = 0.f; }
    else {
      float a = g[(n - mm) & (S - 1)], b = g[(n + mm) & (S - 1)];
      e = 0.5f * (a + b); o = 0.5f * (a - b);
    }
    ev[j] = f2bf(e); ov[j] = f2bf(o);
  }
  *(u16x8*)(Ge + i8) = ev;
  *(u16x8*)(Ge + (long)MEO * KH2 + i8) = ov;
}

// fold x into u,v (transposed): uv[b][d][m] = x[b][m][d] +/- x[b][4096-m][d]
__global__ void k_foldT(const float* __restrict__ x, short* __restrict__ uv) {
  __shared__ float tp[64][65];
  __shared__ float tm[64][65];
  int m0 = blockIdx.x * 64, d0 = blockIdx.y * 64, b = blockIdx.z;
  int t = threadIdx.x;
  int r = t >> 4, c4 = (t & 15) * 4;
#pragma unroll
  for (int rr = 0; rr < 4; ++rr) {
    int m = m0 + r + rr * 16;
    float4 vp = *(const float4*)(x + ((long)(b * S + m)) * DM + d0 + c4);
    int ms = (S - m) & (S - 1);
    float4 vm = *(const float4*)(x + ((long)(b * S + ms)) * DM + d0 + c4);
    tp[r + rr * 16][c4 + 0] = vp.x; tp[r + rr * 16][c4 + 1] = vp.y;
    tp[r + rr * 16][c4 + 2] = vp.z; tp[r + rr * 16][c4 + 3] = vp.w;
    tm[r + rr * 16][c4 + 0] = vm.x; tm[r + rr * 16][c4 + 1] = vm.y;
    tm[r + rr * 16][c4 + 2] = vm.z; tm[r + rr * 16][c4 + 3] = vm.w;
  }
  __syncthreads();
  int m_loc = t & 63, dq = t >> 6;
#pragma unroll
  for (int i = 0; i < 16; ++i) {
    int d_loc = dq * 16 + i;
    int m = m0 + m_loc;
    float P = tp[m_loc][d_loc], M = tm[m_loc][d_loc];
    float u, v;
    if (m == 0 || m == 2048) { u = P; v = 0.f; }
    else if (m > 2048)       { u = 0.f; v = 0.f; }
    else                     { u = P + M; v = P - M; }
    long base = ((long)(b * DM + d0 + d_loc)) * KH2 + m;
    uv[base] = (short)f2bf(u);
    uv[base + (long)4 * DM * KH2] = (short)f2bf(v);
  }
}

// Xs[b][2048][d] = sum_m g[2048-m] * u[b][d][m]; one block per (b,d), LDS tree-reduce
__global__ void k_row2048(const float* __restrict__ g, const short* __restrict__ uv,
                          short* __restrict__ Xs) {
  __shared__ float red[256];
  int bd = blockIdx.x;                 // 0..NB*DM-1
  int b = bd >> 10, d = bd & (DM - 1);
  const short* up = uv + ((long)(b * DM + d)) * KH2;
  int t = threadIdx.x;
  float acc = 0.f;
  for (int m = t; m <= 2048; m += 256)
    acc += g[2048 - m] * bf2f(up[m]);
  red[t] = acc;
  __syncthreads();
  for (int sh = 128; sh > 0; sh >>= 1) {
    if (t < sh) red[t] += red[t + sh];
    __syncthreads();
  }
  if (t == 0) Xs[((long)b * S + 2048) * DM + d] = (short)f2bf(red[0]);
}

// unfold: Xs[b][n] = A[n]+B[n]; Xs[b][4096-n] = A[n]-B[n] (n>0). AB=[8][MEO][DM]
__global__ void k_unfold(const short* __restrict__ AB, short* __restrict__ Xs) {
  long i8 = ((long)blockIdx.x * 256 + threadIdx.x) * 8;
  if (i8 >= (long)NB * MEO * DM) return;
  int b = (int)(i8 >> 21);             // MEO*DM = 2^21
  long rr = i8 & ((1L << 21) - 1);
  int n = (int)(rr >> 10);
  int d = (int)(rr & (DM - 1));
  u16x8 av = *(const u16x8*)(AB + i8);
  u16x8 bv = *(const u16x8*)(AB + ((long)4 * MEO * DM) + i8);
  u16x8 sv, dv;
#pragma unroll
  for (int j = 0; j < 8; ++j) {
    float A = bf2f((short)av[j]), B = bf2f((short)bv[j]);
    sv[j] = f2bf(A + B);
    dv[j] = f2bf(A - B);
  }
  *(u16x8*)(Xs + ((long)b * S + n) * DM + d) = sv;
  if (n > 0)
    *(u16x8*)(Xs + ((long)b * S + (S - n)) * DM + d) = dv;
}

// Mc2[n][m] (n<MH, m<KH, ld KH): (m<=2048) ? cos(2*pi*n*m/S)/64 : 0
__global__ void k_buildM2(const float* __restrict__ cos_tab, short* __restrict__ Mc2) {
  long i8 = ((long)blockIdx.x * 256 + threadIdx.x) * 8;
  if (i8 >= (long)MH * KH) return;
  int n = (int)(i8 / KH);
  int m = (int)(i8 % KH);
  u16x8 mv;
#pragma unroll
  for (int j = 0; j < 8; ++j) {
    int mm = m + j;
    float vv = (mm <= 2048) ? cos_tab[(n * mm) & (S - 1)] * 0.015625f : 0.f;
    mv[j] = f2bf(vv);
  }
  *(u16x8*)(Mc2 + i8) = mv;
}

// W [K][N] fp32 -> WT [N][K] bf16, tiled coalesced transpose
__global__ void k_transW(const float* __restrict__ W, short* __restrict__ WT) {
  __shared__ float tile[64][65];
  int k0 = blockIdx.x * 64, n0 = blockIdx.y * 64;
  int t = threadIdx.x;
  int r = t >> 4, c4 = (t & 15) * 4;
  const float* ip = W + (long)k0 * DM + n0;
#pragma unroll
  for (int rr = 0; rr < 4; ++rr) {
    float4 v = *(const float4*)(ip + (long)(r + rr * 16) * DM + c4);
    tile[r + rr * 16][c4 + 0] = v.x;
    tile[r + rr * 16][c4 + 1] = v.y;
    tile[r + rr * 16][c4 + 2] = v.z;
    tile[r + rr * 16][c4 + 3] = v.w;
  }
  __syncthreads();
  int k_loc = t & 63, nq = t >> 6;
  short* op = WT + (long)n0 * DM + k0;
#pragma unroll
  for (int i = 0; i < 16; ++i) {
    int n_loc = nq * 16 + i;
    op[(long)n_loc * DM + k_loc] = (short)f2bf(tile[k_loc][n_loc]);
  }
}

__global__ void k_logits(const short* __restrict__ Qt, const short* __restrict__ Kt,
                         float* __restrict__ logits) {
  int s = blockIdx.x * 256 + threadIdx.x;
  int h = blockIdx.y, b = blockIdx.z;
  const short* q = Qt + ((long)b * DM + h * HDIM) * S + s;
  const short* k = Kt + ((long)b * DM + h * HDIM) * S + s;
  float acc = 0.f;
#pragma unroll 8
  for (int j = 0; j < HDIM; ++j)
    acc += bf2f(q[(long)j * S]) * bf2f(k[(long)j * S]);
  logits[((long)b * NH + h) * S + s] = acc * 0.125f;
}

__global__ void k_softw(const float* __restrict__ logits, float* __restrict__ w) {
  int idx = blockIdx.x * 256 + threadIdx.x;
  if (idx >= NB * S) return;
  int b = idx >> 12, s = idx & (S - 1);
  const float* lp = logits + (long)b * NH * S + s;
  float v[NH];
  float m = -1e30f;
#pragma unroll
  for (int h = 0; h < NH; ++h) { v[h] = lp[(long)h * S]; m = fmaxf(m, v[h]); }
  float sum = 0.f;
#pragma unroll
  for (int h = 0; h < NH; ++h) { v[h] = expf(v[h] - m); sum += v[h]; }
  float inv = 1.f / sum;
  float* wp = w + (long)b * NH * S + s;
#pragma unroll
  for (int h = 0; h < NH; ++h) wp[(long)h * S] = v[h] * inv;
}

__global__ void k_att(short* vt, const float* __restrict__ wsm) {
  long i8 = ((long)blockIdx.x * 256 + threadIdx.x) * 8;
  if (i8 >= (long)NB * DS) return;
  int b = (int)(i8 >> 22);
  long r = i8 & (DS - 1);
  int d = (int)(r >> 12);
  int s = (int)(r & (S - 1));
  int h = d >> 6;
  const float* wp = wsm + ((long)b * NH + h) * S + s;
  u16x8 vv = *(const u16x8*)(vt + i8);
  u16x8 ov;
#pragma unroll
  for (int j = 0; j < 8; ++j) ov[j] = f2bf(wp[j] * bf2f((short)vv[j]));
  *(u16x8*)(vt + i8) = ov;
}

// A2t[b][d][m] (ld KH): exact column-fold of the ifft cos matrix
__global__ void k_fold(const short* __restrict__ att, short* __restrict__ A2t) {
  int m = blockIdx.x * 256 + threadIdx.x;
  if (m >= KH) return;
  int d = blockIdx.y, b = blockIdx.z;
  const short* ap = att + ((long)b * DM + d) * S;
  float v;
  if (m == 0) v = bf2f(ap[0]);
  else if (m < 2048) v = bf2f(ap[m]) + bf2f(ap[4096 - m]);
  else if (m == 2048) v = bf2f(ap[2048]);
  else v = 0.f;
  A2t[((long)b * DM + d) * KH + m] = (short)f2bf(v);
}

// ---------------- 256x256 8-phase GEMM ----------------
// C = A @ B ; A row-major [M,K] bf16, B TRANSPOSED as Bt [N,K] bf16, ld = K.
// AMIR: A rows via even-symmetry mirror (att_time_half).
// ASEL: A base = A + (bz>>2)*aBatch (even/odd matrix pair), B/C batched by bz.
// WALK: 0 = n-fastest wg walk (B small/L2-resident); 1 = m-fastest (A small, B large).
// EPI 0: bf16 C[M,N] per-batch.
// EPI 1 (C^T orientation): rows = dout in [0,3072), cols = flattened (b,s).
//        Writes bf16 into [b][dout&1023][s] of Cb/Cb2/Cb3 by dout>>10, + bias*bsc.
// EPI 2: fp32 C + bias + resid.
template <int EPI, int AMIR = 0, int ASEL = 0, int WALK = 0>
__global__ __launch_bounds__(512, 2) void gemm8(
    const short* __restrict__ A, const short* __restrict__ Bt,
    short* __restrict__ Cb, short* __restrict__ Cb2, short* __restrict__ Cb3,
    float* __restrict__ Cf,
    const float* __restrict__ bias, const float* __restrict__ bias2,
    const float* __restrict__ bias3,
    const float* __restrict__ bsc, const float* __restrict__ resid,
    int M, int N, int K, long aBatch, long bBatch, long cBatch) {
  __shared__ __align__(16) short As[2][2][256 * 32];   // 64 KiB
  __shared__ __align__(16) short Bs[2][2][256 * 32];   // 64 KiB

  // bijective XCD-chunked remap (nwg % 8 == 0 in all our launches)
  const int gx = gridDim.x, gy = gridDim.y;
  const int nwg = gx * gy * gridDim.z;
  int lin = blockIdx.x + gx * (blockIdx.y + gy * blockIdx.z);
  int wg = lin;
  if ((nwg & 7) == 0) {
    const int cpx = nwg >> 3;
    wg = (lin & 7) * cpx + (lin >> 3);
  }
  const int NTN = N >> 8;
  const int NTM = M >> 8;
  int ntile, mtile, bz;
  if (WALK) {       // m-fastest: B-slab shared by consecutive wgs within n-column
    mtile = wg % NTM;
    const int rest = wg / NTM;
    ntile = rest % NTN;
    bz = rest / NTN;
  } else {          // n-fastest: A-slab shared by consecutive wgs within m-row
    ntile = wg % NTN;
    const int rest = wg / NTN;
    mtile = rest % NTM;
    bz = rest / NTM;
  }

  const short* Ag = ASEL ? (A + (long)(bz >> 2) * aBatch) : (A + (long)bz * aBatch);
  const short* Bg = Bt + (long)bz * bBatch;
  const int m0 = mtile << 8, n0 = ntile << 8;
  const int tid = threadIdx.x;
  const int lane = tid & 63;
  const int wid = tid >> 6;
  const int wm = wid >> 2, wn = wid & 3;

  f32x4 acc[8][4];
#pragma unroll
  for (int i = 0; i < 8; ++i)
#pragma unroll
    for (int j = 0; j < 4; ++j) acc[i][j] = (f32x4){0.f, 0.f, 0.f, 0.f};

  const int NT = K >> 6;
  auto stage = [&](int h) {
    const int tau = h >> 2, q = h & 3;
    const int buf = tau & 1, ks = q >> 1;
    short* ldsbase = (q & 1) ? &Bs[buf][ks][0] : &As[buf][ks][0];
    const short* gsrc = (q & 1) ? Bg : Ag;
    const int row0 = (q & 1) ? n0 : m0;
    const long k0 = (long)tau * 64 + ks * 32;
#pragma unroll
    for (int j = 0; j < 2; ++j) {
      const int o = tid * 16 + j * 8192;
      const int lo = SWZ(o);
      const int row = lo >> 6;
      const int cs = (lo & 63) >> 1;
      const short* gp;
      if (AMIR && !(q & 1)) {
        int grow = row0 + row;
        int b_ = grow >> 12, s_ = grow & (S - 1);
        int sm = (s_ <= 2048) ? s_ : (4096 - s_);
        gp = Ag + ((long)b_ * MH + sm) * K + k0 + cs;
      } else {
        gp = gsrc + (long)(row0 + row) * K + k0 + cs;
      }
      GLOAD(gp, (short*)((char*)ldsbase + o));
    }
  };

  for (int h = 0; h < 7; ++h) stage(h);
  asm volatile("s_waitcnt vmcnt(6)" ::: "memory");
  SBAR();

  short8 bf[4];
  for (int t = 0; t < NT; ++t) {
    const int buf = t & 1;
#pragma unroll
    for (int p = 0; p < 4; ++p) {
      const int ks = p >> 1, mh = p & 1;
      short8 af[4];
      {
        const short* Ah = &As[buf][ks][0];
        const int kb = (lane >> 4) * 16;
        const int r0 = wm * 128 + mh * 64 + (lane & 15);
#pragma unroll
        for (int i = 0; i < 4; ++i) {
          int byte = (r0 + i * 16) * 64 + kb;
          byte = SWZ(byte);
          af[i] = *(const short8*)((const char*)Ah + byte);
        }
        if (mh == 0) {
          const short* Bh = &Bs[buf][ks][0];
          const int c0 = wn * 64 + (lane & 15);
#pragma unroll
          for (int j = 0; j < 4; ++j) {
            int byte = (c0 + j * 16) * 64 + kb;
            byte = SWZ(byte);
            bf[j] = *(const short8*)((const char*)Bh + byte);
          }
        }
      }
      { const int h = 4 * t + p + 7; if (h < 4 * NT) stage(h); }
      SBAR();
      WAITL0();
      __builtin_amdgcn_s_setprio(1);
#pragma unroll
      for (int i = 0; i < 4; ++i)
#pragma unroll
        for (int j = 0; j < 4; ++j)
          acc[mh * 4 + i][j] = __builtin_amdgcn_mfma_f32_16x16x32_bf16(
              af[i], bf[j], acc[mh * 4 + i][j], 0, 0, 0);
      __builtin_amdgcn_s_setprio(0);
      if (p == 3) {
        if (t < NT - 2) {
          asm volatile("s_waitcnt vmcnt(6)" ::: "memory");
        } else if (t == NT - 2) {
          asm volatile("s_waitcnt vmcnt(0)" ::: "memory");
        }
      }
      SBAR();
    }
  }

  // epilogue: C/D layout col = lane&15, row = (lane>>4)*4 + reg
  const int rl = (lane >> 4) << 2;
#pragma unroll
  for (int f = 0; f < 8; ++f) {
    const int rbase = m0 + wm * 128 + f * 16 + rl;
#pragma unroll
    for (int j = 0; j < 4; ++j) {
      const int col = n0 + wn * 64 + j * 16 + (lane & 15);
      f32x4 a = acc[f][j];
      if constexpr (EPI == 0) {
        short* cp = Cb + (long)bz * cBatch;
#pragma unroll
        for (int r = 0; r < 4; ++r)
          cp[(long)(rbase + r) * N + col] = (short)f2bf(a[r]);
      } else if constexpr (EPI == 1) {
        // rows = dout, cols = (b,s): coalesced write along s
        const float sc = bsc ? bsc[0] : 1.f;
        const int b_ = col >> 12;
        const int s_ = col & (S - 1);
#pragma unroll
        for (int r = 0; r < 4; ++r) {
          const int row = rbase + r;
          const int pidx = row >> 10;
          const int d = row & (DM - 1);
          short* Cp = (pidx == 0) ? Cb : ((pidx == 1) ? Cb2 : Cb3);
          const float* bp = (pidx == 0) ? bias : ((pidx == 1) ? bias2 : bias3);
          const float bi = bp ? bp[d] * sc : 0.f;
          Cp[((long)(b_ * DM + d)) * S + s_] = (short)f2bf(a[r] + bi);
        }
      } else {
        float bi = bias[col];
#pragma unroll
        for (int r = 0; r < 4; ++r) {
          long o = (long)(rbase + r) * N + col;
          Cf[o] = a[r] + bi + resid[o];
        }
      }
    }
  }
}

// ---------------- launch ----------------
extern "C" void kernel_launch(void* const* d_in, const int* in_sizes, int n_in,
                              void* d_out, int out_size, void* d_ws, size_t ws_size,
                              hipStream_t stream) {
  const float* x     = (const float*)d_in[0];
  const float* fd    = (const float*)d_in[1];
  const float* Wq    = (const float*)d_in[2];
  const float* bq    = (const float*)d_in[3];
  const float* Wk    = (const float*)d_in[4];
  const float* bk    = (const float*)d_in[5];
  const float* Wv    = (const float*)d_in[6];
  const float* bv    = (const float*)d_in[7];
  const float* Wo    = (const float*)d_in[8];
  const float* bo    = (const float*)d_in[9];
  const float* alpha = (const float*)d_in[10];
  const float* fsc   = (const float*)d_in[11];
  float* out = (float*)d_out;

  // --- workspace layout (~110 MB) ---
  char* wp = (char*)d_ws;
  auto alloc = [&](size_t bytes) {
    char* p = wp;
    wp += (bytes + 255) & ~(size_t)255;
    return p;
  };
  float* cos_tab = (float*)alloc(S * 4);
  float* c_arr   = (float*)alloc(S * 4);          // c_arr[0] = c0 bias factor
  float* g       = (float*)alloc(S * 4);
  float* logits  = (float*)alloc((size_t)NB * NH * S * 4);
  float* wsm     = (float*)alloc((size_t)NB * NH * S * 4);
  short* WTcat = (short*)alloc((size_t)3 * DM * DM * 2);  // [3072][1024]
  short* WoT   = (short*)alloc((size_t)DM * DM * 2);
  short* slotA = (short*)alloc((size_t)NB * DS * 2);  // ABout -> VtT
  short* slotB = (short*)alloc((size_t)NB * DS * 2);  // Ge/Go -> Mc2 + A2t
  short* slotC = (short*)alloc((size_t)NB * DS * 2);  // Xs -> att_half

  // d_out scratch phases: uv (34.6MB) during G-phase; QtT/KtT during attention
  short* uv  = (short*)d_out;                       // [8][DM][KH2]
  short* QtT = (short*)d_out;
  short* KtT = (short*)d_out + (size_t)2 * DS;

  short* Ge  = slotB;                               // [2][MEO][KH2] (Ge,Go)
  short* ABout = slotA;                             // [8][MEO][DM]
  short* Xs  = slotC;
  short* VtT = slotA;
  short* Mc2 = slotB;                               // 9.73 MB
  short* A2t = (short*)((char*)slotB + 10u * 1024 * 1024);
  short* att_half = slotC;

  dim3 blk(256), blk8(512);

  // tables, filter, even/odd matrices, fold
  k_tables<<<dim3(S / 256), blk, 0, stream>>>(fd, alpha, fsc, cos_tab, c_arr);
  k_g<<<dim3(S / 16), blk, 0, stream>>>(cos_tab, c_arr, g);
  k_buildEO<<<dim3((unsigned)((long)MEO * KH2 / 8 / 256)), blk, 0, stream>>>(g, Ge);
  k_foldT<<<dim3(33, DM / 64, NB), blk, 0, stream>>>(x, uv);

  // weight transposes
  k_transW<<<dim3(16, 16), blk, 0, stream>>>(Wq, WTcat);
  k_transW<<<dim3(16, 16), blk, 0, stream>>>(Wk, WTcat + (size_t)DM * DM);
  k_transW<<<dim3(16, 16), blk, 0, stream>>>(Wv, WTcat + (size_t)2 * DM * DM);
  k_transW<<<dim3(16, 16), blk, 0, stream>>>(Wo, WoT);

  // even/odd spectral GEMM: AB[z] = (z<4 ? Ge : Go) @ uv[z]; 256 wg
  dim3 geo(DM / 256, MEO / 256, 8);
  gemm8<0, 0, 1><<<geo, blk8, 0, stream>>>(Ge, uv, ABout, nullptr, nullptr, nullptr,
                                           nullptr, nullptr, nullptr, nullptr, nullptr,
                                           MEO, DM, KH2,
                                           (long)MEO * KH2, (long)DM * KH2, (long)MEO * DM);
  // row n=2048 + unfold mirror into Xs [b][s][d]
  k_row2048<<<dim3(NB * DM), blk, 0, stream>>>(g, uv, Xs);
  k_unfold<<<dim3((unsigned)((long)NB * MEO * DM / 8 / 256)), blk, 0, stream>>>(ABout, Xs);

  // fused q/k/v projections, C^T orientation with m-fastest walk (WALK=1):
  // A = WTcat (6 MB, L2-resident), Bt = Xs (32 MB, each slab read once/XCD-chunk).
  dim3 gqkv(MTOT / 256, 3 * DM / 256, 1);   // (64,12,1) = 768 wg
  gemm8<1, 0, 0, 1><<<gqkv, blk8, 0, stream>>>(WTcat, Xs, QtT, KtT, VtT, nullptr,
                                               bq, bk, bv, c_arr, nullptr,
                                               3 * DM, MTOT, DM, 0, 0, 0);

  // logits, softmax over heads, attended (in-place on v_t)
  k_logits<<<dim3(S / 256, NH, NB), blk, 0, stream>>>(QtT, KtT, logits);
  k_softw<<<dim3(NB * S / 256), blk, 0, stream>>>(logits, wsm);
  k_att<<<dim3((unsigned)((long)NB * DS / 8 / 256)), blk, 0, stream>>>(VtT, wsm);

  // fold att (ifft even symmetry), half-cos matrix, att_time_half = Mc2 @ A2
  k_fold<<<dim3(KH / 256 + 1, DM, NB), blk, 0, stream>>>(VtT, A2t);
  k_buildM2<<<dim3((unsigned)((long)MH * KH / 8 / 256)), blk, 0, stream>>>(cos_tab, Mc2);
  dim3 ghalf(DM / 256, MH / 256, NB);
  gemm8<0><<<ghalf, blk8, 0, stream>>>(Mc2, A2t, att_half, nullptr, nullptr, nullptr,
                                       nullptr, nullptr, nullptr, nullptr, nullptr,
                                       MH, DM, KH, 0, (long)DM * KH, (long)MH * DM);

  // out = att_time @ Wo + bo + x  (A rows via mirror; fp32 epilogue)
  dim3 gproj(DM / 256, MTOT / 256, 1);
  gemm8<2, 1><<<gproj, blk8, 0, stream>>>(att_half, WoT, nullptr, nullptr, nullptr, out,
                                          bo, nullptr, nullptr, nullptr, x,
                                          MTOT, DM, DM, 0, 0, 0);
}

// Round 10
// 413.775 us; speedup vs baseline: 1.1379x; 1.1333x over previous
//
#include <hip/hip_runtime.h>

// ---------------- constants ----------------
#define S      4096
#define DM     1024
#define NB     4
#define NH     16
#define HDIM   64
#define MTOT   (NB * S)          // 16384
#define DS     ((long)DM * S)    // 4,194,304
#define MH     2304              // padded half-rows for Mc2 (2049 used)
#define KH     2112              // folded K for Mc2 (2049 used)
#define KH2    2112              // folded K for even/odd G split (2049 used)
#define MEO    2048              // even/odd GEMM rows (n=0..2047; n=2048 special)

typedef __attribute__((ext_vector_type(8))) short short8;
typedef __attribute__((ext_vector_type(4))) float f32x4;
typedef __attribute__((ext_vector_type(8))) unsigned short u16x8;
typedef __attribute__((ext_vector_type(4))) unsigned short u16x4;

__device__ __forceinline__ unsigned short f2bf(float f) {
  union { float f; unsigned u; } v; v.f = f;
  unsigned r = v.u + 0x7fffu + ((v.u >> 16) & 1u);   // RNE
  return (unsigned short)(r >> 16);
}
__device__ __forceinline__ float bf2f(short h) {
  union { unsigned u; float f; } v; v.u = ((unsigned)(unsigned short)h) << 16;
  return v.f;
}

#define GLOAD(gp, lp) __builtin_amdgcn_global_load_lds( \
    (const __attribute__((address_space(1))) void*)(gp), \
    (__attribute__((address_space(3))) void*)(lp), 16, 0, 0)

#define SBAR() do { asm volatile("" ::: "memory"); __builtin_amdgcn_s_barrier(); \
                    asm volatile("" ::: "memory"); } while (0)
#define WAITL0() asm volatile("s_waitcnt lgkmcnt(0)" ::: "memory")

// LDS swizzle for 64B-row tiles: XOR byte bits 4-5 with row bits 1-2 (byte bits 7-8).
#define SWZ(o) ((o) ^ ((((o) >> 7) & 3) << 4))

// ---------------- small kernels ----------------

__global__ void k_tables(const float* __restrict__ fd, const float* __restrict__ alpha,
                         const float* __restrict__ fsc,
                         float* __restrict__ cos_tab, float* __restrict__ c_arr) {
  int k = blockIdx.x * 256 + threadIdx.x;
  if (k >= S) return;
  float aa = alpha[0] + fsc[0] * (fd[0] - 1.5f);
  const float twopi = 6.28318530717958647692f;
  cos_tab[k] = cosf(twopi * ((float)k / (float)S));
  int kk = (k <= S / 2) ? k : (S - k);
  float af = (float)kk / (float)S;
  c_arr[k] = cosf(aa * atanf(logf(af + 1e-10f)));
}

// g[j] = (1/S) sum_k c[k] cos(2 pi j k / S); 16 lanes per j, deterministic reduce
__global__ void k_g(const float* __restrict__ cos_tab, const float* __restrict__ c_arr,
                    float* __restrict__ g) {
  __shared__ float sct[S];
  __shared__ float sc[S];
  __shared__ float red[16][17];
  for (int i = threadIdx.x; i < S; i += 256) { sct[i] = cos_tab[i]; sc[i] = c_arr[i]; }
  __syncthreads();
  int jl = threadIdx.x >> 4, r = threadIdx.x & 15;
  int j = blockIdx.x * 16 + jl;
  float acc = 0.f;
#pragma unroll 4
  for (int i = 0; i < 256; ++i) {
    int k = r + 16 * i;
    acc += sc[k] * sct[(j * k) & (S - 1)];
  }
  red[jl][r] = acc;
  __syncthreads();
  if (r == 0) {
    float s = 0.f;
#pragma unroll
    for (int i = 0; i < 16; ++i) s += red[jl][i];
    g[j] = s * (1.f / (float)S);
  }
}

// Ge/Go [MEO][KH2] bf16, Go at offset MEO*KH2.
__global__ void k_buildEO(const float* __restrict__ g, short* __restrict__ Ge) {
  long i8 = ((long)blockIdx.x * 256 + threadIdx.x) * 8;
  if (i8 >= (long)MEO * KH2) return;
  int n = (int)(i8 / KH2);
  int m = (int)(i8 % KH2);
  u16x8 ev, ov;
#pragma unroll
  for (int j = 0; j < 8; ++j) {
    int mm = m + j;
    float e, o;
    if (mm == 0)            { e = g[n]; o = 0.f; }
    else if (mm == 2048)    { e = g[(n + 2048) & (S - 1)]; o = 0.f; }
    else if (mm > 2048)     { e = 0.f; o = 0.f; }
    else {
      float a = g[(n - mm) & (S - 1)], b = g[(n + mm) & (S - 1)];
      e = 0.5f * (a + b); o = 0.5f * (a - b);
    }
    ev[j] = f2bf(e); ov[j] = f2bf(o);
  }
  *(u16x8*)(Ge + i8) = ev;
  *(u16x8*)(Ge + (long)MEO * KH2 + i8) = ov;
}

// fold x into u,v (transposed): uv[b][d][m] = x[b][m][d] +/- x[b][4096-m][d]
__global__ void k_foldT(const float* __restrict__ x, short* __restrict__ uv) {
  __shared__ float tp[64][65];
  __shared__ float tm[64][65];
  int m0 = blockIdx.x * 64, d0 = blockIdx.y * 64, b = blockIdx.z;
  int t = threadIdx.x;
  int r = t >> 4, c4 = (t & 15) * 4;
#pragma unroll
  for (int rr = 0; rr < 4; ++rr) {
    int m = m0 + r + rr * 16;
    float4 vp = *(const float4*)(x + ((long)(b * S + m)) * DM + d0 + c4);
    int ms = (S - m) & (S - 1);
    float4 vm = *(const float4*)(x + ((long)(b * S + ms)) * DM + d0 + c4);
    tp[r + rr * 16][c4 + 0] = vp.x; tp[r + rr * 16][c4 + 1] = vp.y;
    tp[r + rr * 16][c4 + 2] = vp.z; tp[r + rr * 16][c4 + 3] = vp.w;
    tm[r + rr * 16][c4 + 0] = vm.x; tm[r + rr * 16][c4 + 1] = vm.y;
    tm[r + rr * 16][c4 + 2] = vm.z; tm[r + rr * 16][c4 + 3] = vm.w;
  }
  __syncthreads();
  int m_loc = t & 63, dq = t >> 6;
#pragma unroll
  for (int i = 0; i < 16; ++i) {
    int d_loc = dq * 16 + i;
    int m = m0 + m_loc;
    float P = tp[m_loc][d_loc], M = tm[m_loc][d_loc];
    float u, v;
    if (m == 0 || m == 2048) { u = P; v = 0.f; }
    else if (m > 2048)       { u = 0.f; v = 0.f; }
    else                     { u = P + M; v = P - M; }
    long base = ((long)(b * DM + d0 + d_loc)) * KH2 + m;
    uv[base] = (short)f2bf(u);
    uv[base + (long)4 * DM * KH2] = (short)f2bf(v);
  }
}

// Xs[b][2048][d] = sum_m g[2048-m] * u[b][d][m]; one block per (b,d), LDS tree-reduce
__global__ void k_row2048(const float* __restrict__ g, const short* __restrict__ uv,
                          short* __restrict__ Xs) {
  __shared__ float red[256];
  int bd = blockIdx.x;                 // 0..NB*DM-1
  int b = bd >> 10, d = bd & (DM - 1);
  const short* up = uv + ((long)(b * DM + d)) * KH2;
  int t = threadIdx.x;
  float acc = 0.f;
  for (int m = t; m <= 2048; m += 256)
    acc += g[2048 - m] * bf2f(up[m]);
  red[t] = acc;
  __syncthreads();
  for (int sh = 128; sh > 0; sh >>= 1) {
    if (t < sh) red[t] += red[t + sh];
    __syncthreads();
  }
  if (t == 0) Xs[((long)b * S + 2048) * DM + d] = (short)f2bf(red[0]);
}

// unfold: Xs[b][n] = A[n]+B[n]; Xs[b][4096-n] = A[n]-B[n] (n>0). AB=[8][MEO][DM]
__global__ void k_unfold(const short* __restrict__ AB, short* __restrict__ Xs) {
  long i8 = ((long)blockIdx.x * 256 + threadIdx.x) * 8;
  if (i8 >= (long)NB * MEO * DM) return;
  int b = (int)(i8 >> 21);             // MEO*DM = 2^21
  long rr = i8 & ((1L << 21) - 1);
  int n = (int)(rr >> 10);
  int d = (int)(rr & (DM - 1));
  u16x8 av = *(const u16x8*)(AB + i8);
  u16x8 bv = *(const u16x8*)(AB + ((long)4 * MEO * DM) + i8);
  u16x8 sv, dv;
#pragma unroll
  for (int j = 0; j < 8; ++j) {
    float A = bf2f((short)av[j]), B = bf2f((short)bv[j]);
    sv[j] = f2bf(A + B);
    dv[j] = f2bf(A - B);
  }
  *(u16x8*)(Xs + ((long)b * S + n) * DM + d) = sv;
  if (n > 0)
    *(u16x8*)(Xs + ((long)b * S + (S - n)) * DM + d) = dv;
}

// Mc2[n][m] (n<MH, m<KH, ld KH): (m<=2048) ? cos(2*pi*n*m/S)/64 : 0
__global__ void k_buildM2(const float* __restrict__ cos_tab, short* __restrict__ Mc2) {
  long i8 = ((long)blockIdx.x * 256 + threadIdx.x) * 8;
  if (i8 >= (long)MH * KH) return;
  int n = (int)(i8 / KH);
  int m = (int)(i8 % KH);
  u16x8 mv;
#pragma unroll
  for (int j = 0; j < 8; ++j) {
    int mm = m + j;
    float vv = (mm <= 2048) ? cos_tab[(n * mm) & (S - 1)] * 0.015625f : 0.f;
    mv[j] = f2bf(vv);
  }
  *(u16x8*)(Mc2 + i8) = mv;
}

// W [K][N] fp32 -> WT [N][K] bf16, tiled coalesced transpose
__global__ void k_transW(const float* __restrict__ W, short* __restrict__ WT) {
  __shared__ float tile[64][65];
  int k0 = blockIdx.x * 64, n0 = blockIdx.y * 64;
  int t = threadIdx.x;
  int r = t >> 4, c4 = (t & 15) * 4;
  const float* ip = W + (long)k0 * DM + n0;
#pragma unroll
  for (int rr = 0; rr < 4; ++rr) {
    float4 v = *(const float4*)(ip + (long)(r + rr * 16) * DM + c4);
    tile[r + rr * 16][c4 + 0] = v.x;
    tile[r + rr * 16][c4 + 1] = v.y;
    tile[r + rr * 16][c4 + 2] = v.z;
    tile[r + rr * 16][c4 + 3] = v.w;
  }
  __syncthreads();
  int k_loc = t & 63, nq = t >> 6;
  short* op = WT + (long)n0 * DM + k0;
#pragma unroll
  for (int i = 0; i < 16; ++i) {
    int n_loc = nq * 16 + i;
    op[(long)n_loc * DM + k_loc] = (short)f2bf(tile[k_loc][n_loc]);
  }
}

__global__ void k_logits(const short* __restrict__ Qt, const short* __restrict__ Kt,
                         float* __restrict__ logits) {
  int s = blockIdx.x * 256 + threadIdx.x;
  int h = blockIdx.y, b = blockIdx.z;
  const short* q = Qt + ((long)b * DM + h * HDIM) * S + s;
  const short* k = Kt + ((long)b * DM + h * HDIM) * S + s;
  float acc = 0.f;
#pragma unroll 8
  for (int j = 0; j < HDIM; ++j)
    acc += bf2f(q[(long)j * S]) * bf2f(k[(long)j * S]);
  logits[((long)b * NH + h) * S + s] = acc * 0.125f;
}

__global__ void k_softw(const float* __restrict__ logits, float* __restrict__ w) {
  int idx = blockIdx.x * 256 + threadIdx.x;
  if (idx >= NB * S) return;
  int b = idx >> 12, s = idx & (S - 1);
  const float* lp = logits + (long)b * NH * S + s;
  float v[NH];
  float m = -1e30f;
#pragma unroll
  for (int h = 0; h < NH; ++h) { v[h] = lp[(long)h * S]; m = fmaxf(m, v[h]); }
  float sum = 0.f;
#pragma unroll
  for (int h = 0; h < NH; ++h) { v[h] = expf(v[h] - m); sum += v[h]; }
  float inv = 1.f / sum;
  float* wp = w + (long)b * NH * S + s;
#pragma unroll
  for (int h = 0; h < NH; ++h) wp[(long)h * S] = v[h] * inv;
}

// fused attend+fold: A2t[b][d][m] = fold_m( w[b][d>>6][.] * vt[b][d][.] ), fp32 fold
__global__ void k_attfold(const short* __restrict__ vt, const float* __restrict__ wsm,
                          short* __restrict__ A2t) {
  int m = blockIdx.x * 256 + threadIdx.x;
  if (m >= KH) return;
  int d = blockIdx.y, b = blockIdx.z;
  const short* vp = vt + ((long)b * DM + d) * S;
  const float* wp = wsm + ((long)b * NH + (d >> 6)) * S;
  float v;
  if (m == 0) v = wp[0] * bf2f(vp[0]);
  else if (m < 2048) v = wp[m] * bf2f(vp[m]) + wp[4096 - m] * bf2f(vp[4096 - m]);
  else if (m == 2048) v = wp[2048] * bf2f(vp[2048]);
  else v = 0.f;
  A2t[((long)b * DM + d) * KH + m] = (short)f2bf(v);
}

// ---------------- 256x256 8-phase GEMM ----------------
// C = A @ B ; A row-major [M,K] bf16, B TRANSPOSED as Bt [N,K] bf16, ld = K.
// AMIR: A rows via even-symmetry mirror (att_time_half).
// ASEL: A base = A + (bz>>2)*aBatch (even/odd matrix pair), B/C batched by bz.
// WALK: 0 = n-fastest wg walk; 1 = m-fastest.
// EPI 0: bf16 C[M,N] per-batch.
// EPI 2: fp32 C + bias + resid.
// EPI 3: QKV epilogue — C rows=(b,s), cols=dout; transpose C-tile through LDS
//        (reusing As/Bs) and write [b][d][s] with dense coalesced 16B stores.
template <int EPI, int AMIR = 0, int ASEL = 0, int WALK = 0>
__global__ __launch_bounds__(512, 2) void gemm8(
    const short* __restrict__ A, const short* __restrict__ Bt,
    short* __restrict__ Cb, short* __restrict__ Cb2, short* __restrict__ Cb3,
    float* __restrict__ Cf,
    const float* __restrict__ bias, const float* __restrict__ bias2,
    const float* __restrict__ bias3,
    const float* __restrict__ bsc, const float* __restrict__ resid,
    int M, int N, int K, long aBatch, long bBatch, long cBatch) {
  __shared__ __align__(16) short SH[65536];   // 128 KiB: A halves then B halves
  auto Ab = [&](int buf, int ks) { return SH + (buf * 2 + ks) * 8192; };
  auto Bb = [&](int buf, int ks) { return SH + 32768 + (buf * 2 + ks) * 8192; };

  // bijective XCD-chunked remap (nwg % 8 == 0 in all our launches)
  const int gx = gridDim.x, gy = gridDim.y;
  const int nwg = gx * gy * gridDim.z;
  int lin = blockIdx.x + gx * (blockIdx.y + gy * blockIdx.z);
  int wg = lin;
  if ((nwg & 7) == 0) {
    const int cpx = nwg >> 3;
    wg = (lin & 7) * cpx + (lin >> 3);
  }
  const int NTN = N >> 8;
  const int NTM = M >> 8;
  int ntile, mtile, bz;
  if (WALK) {
    mtile = wg % NTM;
    const int rest = wg / NTM;
    ntile = rest % NTN;
    bz = rest / NTN;
  } else {
    ntile = wg % NTN;
    const int rest = wg / NTN;
    mtile = rest % NTM;
    bz = rest / NTM;
  }

  const short* Ag = ASEL ? (A + (long)(bz >> 2) * aBatch) : (A + (long)bz * aBatch);
  const short* Bg = Bt + (long)bz * bBatch;
  const int m0 = mtile << 8, n0 = ntile << 8;
  const int tid = threadIdx.x;
  const int lane = tid & 63;
  const int wid = tid >> 6;
  const int wm = wid >> 2, wn = wid & 3;

  f32x4 acc[8][4];
#pragma unroll
  for (int i = 0; i < 8; ++i)
#pragma unroll
    for (int j = 0; j < 4; ++j) acc[i][j] = (f32x4){0.f, 0.f, 0.f, 0.f};

  const int NT = K >> 6;
  auto stage = [&](int h) {
    const int tau = h >> 2, q = h & 3;
    const int buf = tau & 1, ks = q >> 1;
    short* ldsbase = (q & 1) ? Bb(buf, ks) : Ab(buf, ks);
    const short* gsrc = (q & 1) ? Bg : Ag;
    const int row0 = (q & 1) ? n0 : m0;
    const long k0 = (long)tau * 64 + ks * 32;
#pragma unroll
    for (int j = 0; j < 2; ++j) {
      const int o = tid * 16 + j * 8192;
      const int lo = SWZ(o);
      const int row = lo >> 6;
      const int cs = (lo & 63) >> 1;
      const short* gp;
      if (AMIR && !(q & 1)) {
        int grow = row0 + row;
        int b_ = grow >> 12, s_ = grow & (S - 1);
        int sm = (s_ <= 2048) ? s_ : (4096 - s_);
        gp = Ag + ((long)b_ * MH + sm) * K + k0 + cs;
      } else {
        gp = gsrc + (long)(row0 + row) * K + k0 + cs;
      }
      GLOAD(gp, (short*)((char*)ldsbase + o));
    }
  };

  for (int h = 0; h < 7; ++h) stage(h);
  asm volatile("s_waitcnt vmcnt(6)" ::: "memory");
  SBAR();

  short8 bf[4];
  for (int t = 0; t < NT; ++t) {
    const int buf = t & 1;
#pragma unroll
    for (int p = 0; p < 4; ++p) {
      const int ks = p >> 1, mh = p & 1;
      short8 af[4];
      {
        const short* Ah = Ab(buf, ks);
        const int kb = (lane >> 4) * 16;
        const int r0 = wm * 128 + mh * 64 + (lane & 15);
#pragma unroll
        for (int i = 0; i < 4; ++i) {
          int byte = (r0 + i * 16) * 64 + kb;
          byte = SWZ(byte);
          af[i] = *(const short8*)((const char*)Ah + byte);
        }
        if (mh == 0) {
          const short* Bh = Bb(buf, ks);
          const int c0 = wn * 64 + (lane & 15);
#pragma unroll
          for (int j = 0; j < 4; ++j) {
            int byte = (c0 + j * 16) * 64 + kb;
            byte = SWZ(byte);
            bf[j] = *(const short8*)((const char*)Bh + byte);
          }
        }
      }
      { const int h = 4 * t + p + 7; if (h < 4 * NT) stage(h); }
      SBAR();
      WAITL0();
      __builtin_amdgcn_s_setprio(1);
#pragma unroll
      for (int i = 0; i < 4; ++i)
#pragma unroll
        for (int j = 0; j < 4; ++j)
          acc[mh * 4 + i][j] = __builtin_amdgcn_mfma_f32_16x16x32_bf16(
              af[i], bf[j], acc[mh * 4 + i][j], 0, 0, 0);
      __builtin_amdgcn_s_setprio(0);
      if (p == 3) {
        if (t < NT - 2) {
          asm volatile("s_waitcnt vmcnt(6)" ::: "memory");
        } else if (t == NT - 2) {
          asm volatile("s_waitcnt vmcnt(0)" ::: "memory");
        }
      }
      SBAR();
    }
  }

  const int rl = (lane >> 4) << 2;

  if constexpr (EPI == 3) {
    // phase 1: acc -> LDS transposed [lc=dout][lr=s], swizzled; all K-loop LDS
    // reads completed before the loop's final barrier, so overwrite is safe.
    const int b_ = m0 >> 12;
    const int s0 = m0 & (S - 1);
    const int pidx = n0 >> 10;
    const int d0 = n0 & (DM - 1);
    const float* bp = (pidx == 0) ? bias : ((pidx == 1) ? bias2 : bias3);
    short* Cp = (pidx == 0) ? Cb : ((pidx == 1) ? Cb2 : Cb3);
    const float sc = bsc ? bsc[0] : 1.f;
#pragma unroll
    for (int f = 0; f < 8; ++f) {
      const int lr0 = wm * 128 + f * 16 + rl;
#pragma unroll
      for (int j = 0; j < 4; ++j) {
        const int lc = wn * 64 + j * 16 + (lane & 15);
        const float bi = bp[d0 + lc] * sc;
        f32x4 a = acc[f][j];
        u16x4 pk;
#pragma unroll
        for (int r = 0; r < 4; ++r) pk[r] = f2bf(a[r] + bi);
        int ad = lc * 512 + lr0 * 2;
        ad ^= (lc & 7) << 4;
        *(u16x4*)((char*)SH + ad) = pk;
      }
    }
    __syncthreads();
    // phase 2: dense coalesced stores — each wave writes 2 full 512B rows/inst
    const long gbase = ((long)(b_ * DM + d0)) * S + s0;
#pragma unroll
    for (int it = 0; it < 16; ++it) {
      const int lc = wid * 32 + (it << 1) + (lane >> 5);
      const int lr = (lane & 31) * 8;
      int ad = lc * 512 + lr * 2;
      ad ^= (lc & 7) << 4;
      u16x8 vv = *(u16x8*)((char*)SH + ad);
      *(u16x8*)(Cp + gbase + (long)lc * S + lr) = vv;
    }
    return;
  }

  // epilogue (EPI 0/2): C/D layout col = lane&15, row = (lane>>4)*4 + reg
#pragma unroll
  for (int f = 0; f < 8; ++f) {
    const int rbase = m0 + wm * 128 + f * 16 + rl;
#pragma unroll
    for (int j = 0; j < 4; ++j) {
      const int col = n0 + wn * 64 + j * 16 + (lane & 15);
      f32x4 a = acc[f][j];
      if constexpr (EPI == 0) {
        short* cp = Cb + (long)bz * cBatch;
#pragma unroll
        for (int r = 0; r < 4; ++r)
          cp[(long)(rbase + r) * N + col] = (short)f2bf(a[r]);
      } else {
        float bi = bias[col];
#pragma unroll
        for (int r = 0; r < 4; ++r) {
          long o = (long)(rbase + r) * N + col;
          Cf[o] = a[r] + bi + resid[o];
        }
      }
    }
  }
}

// ---------------- launch ----------------
extern "C" void kernel_launch(void* const* d_in, const int* in_sizes, int n_in,
                              void* d_out, int out_size, void* d_ws, size_t ws_size,
                              hipStream_t stream) {
  const float* x     = (const float*)d_in[0];
  const float* fd    = (const float*)d_in[1];
  const float* Wq    = (const float*)d_in[2];
  const float* bq    = (const float*)d_in[3];
  const float* Wk    = (const float*)d_in[4];
  const float* bk    = (const float*)d_in[5];
  const float* Wv    = (const float*)d_in[6];
  const float* bv    = (const float*)d_in[7];
  const float* Wo    = (const float*)d_in[8];
  const float* bo    = (const float*)d_in[9];
  const float* alpha = (const float*)d_in[10];
  const float* fsc   = (const float*)d_in[11];
  float* out = (float*)d_out;

  // --- workspace layout (~110 MB) ---
  char* wp = (char*)d_ws;
  auto alloc = [&](size_t bytes) {
    char* p = wp;
    wp += (bytes + 255) & ~(size_t)255;
    return p;
  };
  float* cos_tab = (float*)alloc(S * 4);
  float* c_arr   = (float*)alloc(S * 4);          // c_arr[0] = c0 bias factor
  float* g       = (float*)alloc(S * 4);
  float* logits  = (float*)alloc((size_t)NB * NH * S * 4);
  float* wsm     = (float*)alloc((size_t)NB * NH * S * 4);
  short* WTcat = (short*)alloc((size_t)3 * DM * DM * 2);  // [3072][1024]
  short* WoT   = (short*)alloc((size_t)DM * DM * 2);
  short* slotA = (short*)alloc((size_t)NB * DS * 2);  // ABout -> VtT
  short* slotB = (short*)alloc((size_t)NB * DS * 2);  // Ge/Go -> Mc2 + A2t
  short* slotC = (short*)alloc((size_t)NB * DS * 2);  // Xs -> att_half

  // d_out scratch phases: uv (34.6MB) during G-phase; QtT/KtT during attention
  short* uv  = (short*)d_out;                       // [8][DM][KH2]
  short* QtT = (short*)d_out;
  short* KtT = (short*)d_out + (size_t)2 * DS;

  short* Ge  = slotB;                               // [2][MEO][KH2] (Ge,Go)
  short* ABout = slotA;                             // [8][MEO][DM]
  short* Xs  = slotC;
  short* VtT = slotA;
  short* Mc2 = slotB;                               // 9.73 MB
  short* A2t = (short*)((char*)slotB + 10u * 1024 * 1024);
  short* att_half = slotC;

  dim3 blk(256), blk8(512);

  // tables, filter, even/odd matrices, fold
  k_tables<<<dim3(S / 256), blk, 0, stream>>>(fd, alpha, fsc, cos_tab, c_arr);
  k_g<<<dim3(S / 16), blk, 0, stream>>>(cos_tab, c_arr, g);
  k_buildEO<<<dim3((unsigned)((long)MEO * KH2 / 8 / 256)), blk, 0, stream>>>(g, Ge);
  k_foldT<<<dim3(33, DM / 64, NB), blk, 0, stream>>>(x, uv);

  // weight transposes
  k_transW<<<dim3(16, 16), blk, 0, stream>>>(Wq, WTcat);
  k_transW<<<dim3(16, 16), blk, 0, stream>>>(Wk, WTcat + (size_t)DM * DM);
  k_transW<<<dim3(16, 16), blk, 0, stream>>>(Wv, WTcat + (size_t)2 * DM * DM);
  k_transW<<<dim3(16, 16), blk, 0, stream>>>(Wo, WoT);

  // even/odd spectral GEMM: AB[z] = (z<4 ? Ge : Go) @ uv[z]; 256 wg
  dim3 geo(DM / 256, MEO / 256, 8);
  gemm8<0, 0, 1><<<geo, blk8, 0, stream>>>(Ge, uv, ABout, nullptr, nullptr, nullptr,
                                           nullptr, nullptr, nullptr, nullptr, nullptr,
                                           MEO, DM, KH2,
                                           (long)MEO * KH2, (long)DM * KH2, (long)MEO * DM);
  // row n=2048 + unfold mirror into Xs [b][s][d]
  k_row2048<<<dim3(NB * DM), blk, 0, stream>>>(g, uv, Xs);
  k_unfold<<<dim3((unsigned)((long)NB * MEO * DM / 8 / 256)), blk, 0, stream>>>(ABout, Xs);

  // fused q/k/v projections (A = Xs, B = WTcat L2-resident, n-fastest walk),
  // EPI=3: LDS-transposed epilogue -> dense coalesced [b][d][s] writes
  dim3 gqkv(3 * DM / 256, MTOT / 256, 1);   // (12,64,1) = 768 wg
  gemm8<3><<<gqkv, blk8, 0, stream>>>(Xs, WTcat, QtT, KtT, VtT, nullptr,
                                      bq, bk, bv, c_arr, nullptr,
                                      MTOT, 3 * DM, DM, 0, 0, 0);

  // logits, softmax over heads, fused attend+fold
  k_logits<<<dim3(S / 256, NH, NB), blk, 0, stream>>>(QtT, KtT, logits);
  k_softw<<<dim3(NB * S / 256), blk, 0, stream>>>(logits, wsm);
  k_attfold<<<dim3(KH / 256 + 1, DM, NB), blk, 0, stream>>>(VtT, wsm, A2t);

  // half-cos matrix, att_time_half = Mc2 @ A2
  k_buildM2<<<dim3((unsigned)((long)MH * KH / 8 / 256)), blk, 0, stream>>>(cos_tab, Mc2);
  dim3 ghalf(DM / 256, MH / 256, NB);
  gemm8<0><<<ghalf, blk8, 0, stream>>>(Mc2, A2t, att_half, nullptr, nullptr, nullptr,
                                       nullptr, nullptr, nullptr, nullptr, nullptr,
                                       MH, DM, KH, 0, (long)DM * KH, (long)MH * DM);

  // out = att_time @ Wo + bo + x  (A rows via mirror; fp32 epilogue)
  dim3 gproj(DM / 256, MTOT / 256, 1);
  gemm8<2, 1><<<gproj, blk8, 0, stream>>>(att_half, WoT, nullptr, nullptr, nullptr, out,
                                          bo, nullptr, nullptr, nullptr, x,
                                          MTOT, DM, DM, 0, 0, 0);
}

// Round 11
// 410.688 us; speedup vs baseline: 1.1465x; 1.0075x over previous
//
#include <hip/hip_runtime.h>

// ---------------- constants ----------------
#define S      4096
#define DM     1024
#define NB     4
#define NH     16
#define HDIM   64
#define MTOT   (NB * S)          // 16384
#define DS     ((long)DM * S)    // 4,194,304
#define MH     2304              // padded half-rows for Mc2 (2049 used)
#define KH     2112              // folded K for Mc2 (2049 used)
#define KH2    2112              // folded K for even/odd G split (2049 used)
#define MEO    2048              // even/odd GEMM rows (n=0..2047; n=2048 special)

typedef __attribute__((ext_vector_type(8))) short short8;
typedef __attribute__((ext_vector_type(4))) float f32x4;
typedef __attribute__((ext_vector_type(8))) unsigned short u16x8;
typedef __attribute__((ext_vector_type(4))) unsigned short u16x4;

__device__ __forceinline__ unsigned short f2bf(float f) {
  union { float f; unsigned u; } v; v.f = f;
  unsigned r = v.u + 0x7fffu + ((v.u >> 16) & 1u);   // RNE
  return (unsigned short)(r >> 16);
}
__device__ __forceinline__ float bf2f(short h) {
  union { unsigned u; float f; } v; v.u = ((unsigned)(unsigned short)h) << 16;
  return v.f;
}

#define GLOAD(gp, lp) __builtin_amdgcn_global_load_lds( \
    (const __attribute__((address_space(1))) void*)(gp), \
    (__attribute__((address_space(3))) void*)(lp), 16, 0, 0)

#define SBAR() do { asm volatile("" ::: "memory"); __builtin_amdgcn_s_barrier(); \
                    asm volatile("" ::: "memory"); } while (0)
#define WAITL0() asm volatile("s_waitcnt lgkmcnt(0)" ::: "memory")

// LDS swizzle for 64B-row tiles: XOR byte bits 4-5 with row bits 1-2 (byte bits 7-8).
#define SWZ(o) ((o) ^ ((((o) >> 7) & 3) << 4))

// ---------------- small kernels ----------------

__global__ void k_tables(const float* __restrict__ fd, const float* __restrict__ alpha,
                         const float* __restrict__ fsc,
                         float* __restrict__ cos_tab, float* __restrict__ c_arr) {
  int k = blockIdx.x * 256 + threadIdx.x;
  if (k >= S) return;
  float aa = alpha[0] + fsc[0] * (fd[0] - 1.5f);
  const float twopi = 6.28318530717958647692f;
  cos_tab[k] = cosf(twopi * ((float)k / (float)S));
  int kk = (k <= S / 2) ? k : (S - k);
  float af = (float)kk / (float)S;
  c_arr[k] = cosf(aa * atanf(logf(af + 1e-10f)));
}

// g[j] = (1/S) sum_k c[k] cos(2 pi j k / S); 16 lanes per j, deterministic reduce
__global__ void k_g(const float* __restrict__ cos_tab, const float* __restrict__ c_arr,
                    float* __restrict__ g) {
  __shared__ float sct[S];
  __shared__ float sc[S];
  __shared__ float red[16][17];
  for (int i = threadIdx.x; i < S; i += 256) { sct[i] = cos_tab[i]; sc[i] = c_arr[i]; }
  __syncthreads();
  int jl = threadIdx.x >> 4, r = threadIdx.x & 15;
  int j = blockIdx.x * 16 + jl;
  float acc = 0.f;
#pragma unroll 4
  for (int i = 0; i < 256; ++i) {
    int k = r + 16 * i;
    acc += sc[k] * sct[(j * k) & (S - 1)];
  }
  red[jl][r] = acc;
  __syncthreads();
  if (r == 0) {
    float s = 0.f;
#pragma unroll
    for (int i = 0; i < 16; ++i) s += red[jl][i];
    g[j] = s * (1.f / (float)S);
  }
}

// Ge/Go [MEO][KH2] bf16, Go at offset MEO*KH2.
__global__ void k_buildEO(const float* __restrict__ g, short* __restrict__ Ge) {
  long i8 = ((long)blockIdx.x * 256 + threadIdx.x) * 8;
  if (i8 >= (long)MEO * KH2) return;
  int n = (int)(i8 / KH2);
  int m = (int)(i8 % KH2);
  u16x8 ev, ov;
#pragma unroll
  for (int j = 0; j < 8; ++j) {
    int mm = m + j;
    float e, o;
    if (mm == 0)            { e = g[n]; o = 0.f; }
    else if (mm == 2048)    { e = g[(n + 2048) & (S - 1)]; o = 0.f; }
    else if (mm > 2048)     { e = 0.f; o = 0.f; }
    else {
      float a = g[(n - mm) & (S - 1)], b = g[(n + mm) & (S - 1)];
      e = 0.5f * (a + b); o = 0.5f * (a - b);
    }
    ev[j] = f2bf(e); ov[j] = f2bf(o);
  }
  *(u16x8*)(Ge + i8) = ev;
  *(u16x8*)(Ge + (long)MEO * KH2 + i8) = ov;
}

// fold x into u,v (transposed): uv[b][d][m] = x[b][m][d] +/- x[b][4096-m][d]
__global__ void k_foldT(const float* __restrict__ x, short* __restrict__ uv) {
  __shared__ float tp[64][65];
  __shared__ float tm[64][65];
  int m0 = blockIdx.x * 64, d0 = blockIdx.y * 64, b = blockIdx.z;
  int t = threadIdx.x;
  int r = t >> 4, c4 = (t & 15) * 4;
#pragma unroll
  for (int rr = 0; rr < 4; ++rr) {
    int m = m0 + r + rr * 16;
    float4 vp = *(const float4*)(x + ((long)(b * S + m)) * DM + d0 + c4);
    int ms = (S - m) & (S - 1);
    float4 vm = *(const float4*)(x + ((long)(b * S + ms)) * DM + d0 + c4);
    tp[r + rr * 16][c4 + 0] = vp.x; tp[r + rr * 16][c4 + 1] = vp.y;
    tp[r + rr * 16][c4 + 2] = vp.z; tp[r + rr * 16][c4 + 3] = vp.w;
    tm[r + rr * 16][c4 + 0] = vm.x; tm[r + rr * 16][c4 + 1] = vm.y;
    tm[r + rr * 16][c4 + 2] = vm.z; tm[r + rr * 16][c4 + 3] = vm.w;
  }
  __syncthreads();
  int m_loc = t & 63, dq = t >> 6;
#pragma unroll
  for (int i = 0; i < 16; ++i) {
    int d_loc = dq * 16 + i;
    int m = m0 + m_loc;
    float P = tp[m_loc][d_loc], M = tm[m_loc][d_loc];
    float u, v;
    if (m == 0 || m == 2048) { u = P; v = 0.f; }
    else if (m > 2048)       { u = 0.f; v = 0.f; }
    else                     { u = P + M; v = P - M; }
    long base = ((long)(b * DM + d0 + d_loc)) * KH2 + m;
    uv[base] = (short)f2bf(u);
    uv[base + (long)4 * DM * KH2] = (short)f2bf(v);
  }
}

// merged: blocks [0,4096): unfold AB -> Xs; blocks [4096,8192): row n=2048 dot
__global__ void k_unfold2(const short* __restrict__ AB, const float* __restrict__ g,
                          const short* __restrict__ uv, short* __restrict__ Xs) {
  __shared__ float red[256];
  int bx = blockIdx.x;
  if (bx < 4096) {
    long i8 = ((long)bx * 256 + threadIdx.x) * 8;
    int b = (int)(i8 >> 21);             // MEO*DM = 2^21
    long rr = i8 & ((1L << 21) - 1);
    int n = (int)(rr >> 10);
    int d = (int)(rr & (DM - 1));
    u16x8 av = *(const u16x8*)(AB + i8);
    u16x8 bv = *(const u16x8*)(AB + ((long)4 * MEO * DM) + i8);
    u16x8 sv, dv;
#pragma unroll
    for (int j = 0; j < 8; ++j) {
      float A = bf2f((short)av[j]), B = bf2f((short)bv[j]);
      sv[j] = f2bf(A + B);
      dv[j] = f2bf(A - B);
    }
    *(u16x8*)(Xs + ((long)b * S + n) * DM + d) = sv;
    if (n > 0)
      *(u16x8*)(Xs + ((long)b * S + (S - n)) * DM + d) = dv;
  } else {
    int bd = bx - 4096;                  // 0..NB*DM-1
    int b = bd >> 10, d = bd & (DM - 1);
    const short* up = uv + ((long)(b * DM + d)) * KH2;
    int t = threadIdx.x;
    float acc = 0.f;
    for (int m = t; m <= 2048; m += 256)
      acc += g[2048 - m] * bf2f(up[m]);
    red[t] = acc;
    __syncthreads();
    for (int sh = 128; sh > 0; sh >>= 1) {
      if (t < sh) red[t] += red[t + sh];
      __syncthreads();
    }
    if (t == 0) Xs[((long)b * S + 2048) * DM + d] = (short)f2bf(red[0]);
  }
}

// Mc2[n][m] (n<MH, m<KH, ld KH): (m<=2048) ? cos(2*pi*n*m/S)/64 : 0
__global__ void k_buildM2(const float* __restrict__ cos_tab, short* __restrict__ Mc2) {
  long i8 = ((long)blockIdx.x * 256 + threadIdx.x) * 8;
  if (i8 >= (long)MH * KH) return;
  int n = (int)(i8 / KH);
  int m = (int)(i8 % KH);
  u16x8 mv;
#pragma unroll
  for (int j = 0; j < 8; ++j) {
    int mm = m + j;
    float vv = (mm <= 2048) ? cos_tab[(n * mm) & (S - 1)] * 0.015625f : 0.f;
    mv[j] = f2bf(vv);
  }
  *(u16x8*)(Mc2 + i8) = mv;
}

// all 4 weights: W[z] [K][N] fp32 -> WT + z*DM*DM as [N][K] bf16
__global__ void k_transW4(const float* __restrict__ W0, const float* __restrict__ W1,
                          const float* __restrict__ W2, const float* __restrict__ W3,
                          short* __restrict__ WT) {
  __shared__ float tile[64][65];
  int z = blockIdx.z;
  const float* W = (z == 0) ? W0 : ((z == 1) ? W1 : ((z == 2) ? W2 : W3));
  short* WTo = WT + (size_t)z * DM * DM;
  int k0 = blockIdx.x * 64, n0 = blockIdx.y * 64;
  int t = threadIdx.x;
  int r = t >> 4, c4 = (t & 15) * 4;
  const float* ip = W + (long)k0 * DM + n0;
#pragma unroll
  for (int rr = 0; rr < 4; ++rr) {
    float4 v = *(const float4*)(ip + (long)(r + rr * 16) * DM + c4);
    tile[r + rr * 16][c4 + 0] = v.x;
    tile[r + rr * 16][c4 + 1] = v.y;
    tile[r + rr * 16][c4 + 2] = v.z;
    tile[r + rr * 16][c4 + 3] = v.w;
  }
  __syncthreads();
  int k_loc = t & 63, nq = t >> 6;
  short* op = WTo + (long)n0 * DM + k0;
#pragma unroll
  for (int i = 0; i < 16; ++i) {
    int n_loc = nq * 16 + i;
    op[(long)n_loc * DM + k_loc] = (short)f2bf(tile[k_loc][n_loc]);
  }
}

// fused logits+head-softmax. Q,K in natural [(b,s)][DM] layout.
// 16 threads per token, one head each; shfl_xor width-16 softmax.
__global__ void k_logsoft(const short* __restrict__ Q, const short* __restrict__ K,
                          float* __restrict__ w) {
  int idx = blockIdx.x * 16 + (threadIdx.x >> 4);   // (b,s) 0..16383
  int h = threadIdx.x & 15;
  const short* q = Q + (long)idx * DM + h * HDIM;
  const short* k = K + (long)idx * DM + h * HDIM;
  float acc = 0.f;
#pragma unroll
  for (int jj = 0; jj < 8; ++jj) {
    u16x8 qa = *(const u16x8*)(q + jj * 8);
    u16x8 ka = *(const u16x8*)(k + jj * 8);
#pragma unroll
    for (int l = 0; l < 8; ++l) acc += bf2f((short)qa[l]) * bf2f((short)ka[l]);
  }
  acc *= 0.125f;
  float m = acc;
#pragma unroll
  for (int d = 1; d < 16; d <<= 1) m = fmaxf(m, __shfl_xor(m, d, 16));
  float e = expf(acc - m);
  float ssum = e;
#pragma unroll
  for (int d = 1; d < 16; d <<= 1) ssum += __shfl_xor(ssum, d, 16);
  int b = idx >> 12, s = idx & (S - 1);
  w[((long)b * NH + h) * S + s] = e / ssum;
}

// fused attend+fold, tiled transpose. V natural [(b,s)][DM] -> A2t[b][d][m].
__global__ void k_attfold2(const short* __restrict__ V, const float* __restrict__ wsm,
                           short* __restrict__ A2t) {
  __shared__ float t1[64][65];
  __shared__ float t2[64][65];
  __shared__ float w1[64], w2[64];
  int m0 = blockIdx.x * 64, d0 = blockIdx.y * 64, b = blockIdx.z;
  int t = threadIdx.x;
  int h0 = d0 >> 6;
  if (t < 64) {
    int m = m0 + t;
    const float* wp = wsm + ((long)b * NH + h0) * S;
    w1[t] = wp[m & (S - 1)];
    w2[t] = wp[(S - m) & (S - 1)];
  }
  int r = t >> 4, c4 = (t & 15) * 4;
#pragma unroll
  for (int rr = 0; rr < 4; ++rr) {
    int i = r + rr * 16;
    int m = m0 + i;
    u16x4 a = *(const u16x4*)(V + ((long)(b * S + (m & (S - 1)))) * DM + d0 + c4);
    u16x4 bb = *(const u16x4*)(V + ((long)(b * S + ((S - m) & (S - 1)))) * DM + d0 + c4);
#pragma unroll
    for (int l = 0; l < 4; ++l) {
      t1[i][c4 + l] = bf2f((short)a[l]);
      t2[i][c4 + l] = bf2f((short)bb[l]);
    }
  }
  __syncthreads();
  int i_loc = t & 63, jq = t >> 6;
  int m = m0 + i_loc;
#pragma unroll
  for (int jj = 0; jj < 16; ++jj) {
    int j = jq * 16 + jj;
    float rv;
    if (m == 0 || m == 2048) rv = w1[i_loc] * t1[i_loc][j];
    else if (m < 2048)       rv = w1[i_loc] * t1[i_loc][j] + w2[i_loc] * t2[i_loc][j];
    else                     rv = 0.f;
    A2t[((long)(b * DM + d0 + j)) * KH + m] = (short)f2bf(rv);
  }
}

// ---------------- 256x256 8-phase GEMM ----------------
// C = A @ B ; A row-major [M,K] bf16, B TRANSPOSED as Bt [N,K] bf16, ld = K.
// AMIR: A rows via even-symmetry mirror (att_time_half).
// ASEL: A base = A + (bz>>2)*aBatch (even/odd matrix pair), B/C batched by bz.
// WALK: 0 = n-fastest wg walk; 1 = m-fastest.
// EPI 0: bf16 C[M,N] per-batch.
// EPI 2: fp32 C + bias + resid.
// EPI 4: QKV natural layout — rows=(b,s), col=dout; write Cb/Cb2/Cb3 by col>>10
//        at [row][col&1023] (ld=DM) + bias*bsc.
template <int EPI, int AMIR = 0, int ASEL = 0, int WALK = 0>
__global__ __launch_bounds__(512, 2) void gemm8(
    const short* __restrict__ A, const short* __restrict__ Bt,
    short* __restrict__ Cb, short* __restrict__ Cb2, short* __restrict__ Cb3,
    float* __restrict__ Cf,
    const float* __restrict__ bias, const float* __restrict__ bias2,
    const float* __restrict__ bias3,
    const float* __restrict__ bsc, const float* __restrict__ resid,
    int M, int N, int K, long aBatch, long bBatch, long cBatch) {
  __shared__ __align__(16) short SH[65536];   // 128 KiB: A halves then B halves
  auto Ab = [&](int buf, int ks) { return SH + (buf * 2 + ks) * 8192; };
  auto Bb = [&](int buf, int ks) { return SH + 32768 + (buf * 2 + ks) * 8192; };

  // bijective XCD-chunked remap (nwg % 8 == 0 in all our launches)
  const int gx = gridDim.x, gy = gridDim.y;
  const int nwg = gx * gy * gridDim.z;
  int lin = blockIdx.x + gx * (blockIdx.y + gy * blockIdx.z);
  int wg = lin;
  if ((nwg & 7) == 0) {
    const int cpx = nwg >> 3;
    wg = (lin & 7) * cpx + (lin >> 3);
  }
  const int NTN = N >> 8;
  const int NTM = M >> 8;
  int ntile, mtile, bz;
  if (WALK) {
    mtile = wg % NTM;
    const int rest = wg / NTM;
    ntile = rest % NTN;
    bz = rest / NTN;
  } else {
    ntile = wg % NTN;
    const int rest = wg / NTN;
    mtile = rest % NTM;
    bz = rest / NTM;
  }

  const short* Ag = ASEL ? (A + (long)(bz >> 2) * aBatch) : (A + (long)bz * aBatch);
  const short* Bg = Bt + (long)bz * bBatch;
  const int m0 = mtile << 8, n0 = ntile << 8;
  const int tid = threadIdx.x;
  const int lane = tid & 63;
  const int wid = tid >> 6;
  const int wm = wid >> 2, wn = wid & 3;

  f32x4 acc[8][4];
#pragma unroll
  for (int i = 0; i < 8; ++i)
#pragma unroll
    for (int j = 0; j < 4; ++j) acc[i][j] = (f32x4){0.f, 0.f, 0.f, 0.f};

  const int NT = K >> 6;
  auto stage = [&](int h) {
    const int tau = h >> 2, q = h & 3;
    const int buf = tau & 1, ks = q >> 1;
    short* ldsbase = (q & 1) ? Bb(buf, ks) : Ab(buf, ks);
    const short* gsrc = (q & 1) ? Bg : Ag;
    const int row0 = (q & 1) ? n0 : m0;
    const long k0 = (long)tau * 64 + ks * 32;
#pragma unroll
    for (int j = 0; j < 2; ++j) {
      const int o = tid * 16 + j * 8192;
      const int lo = SWZ(o);
      const int row = lo >> 6;
      const int cs = (lo & 63) >> 1;
      const short* gp;
      if (AMIR && !(q & 1)) {
        int grow = row0 + row;
        int b_ = grow >> 12, s_ = grow & (S - 1);
        int sm = (s_ <= 2048) ? s_ : (4096 - s_);
        gp = Ag + ((long)b_ * MH + sm) * K + k0 + cs;
      } else {
        gp = gsrc + (long)(row0 + row) * K + k0 + cs;
      }
      GLOAD(gp, (short*)((char*)ldsbase + o));
    }
  };

  for (int h = 0; h < 7; ++h) stage(h);
  asm volatile("s_waitcnt vmcnt(6)" ::: "memory");
  SBAR();

  short8 bf[4];
  for (int t = 0; t < NT; ++t) {
    const int buf = t & 1;
#pragma unroll
    for (int p = 0; p < 4; ++p) {
      const int ks = p >> 1, mh = p & 1;
      short8 af[4];
      {
        const short* Ah = Ab(buf, ks);
        const int kb = (lane >> 4) * 16;
        const int r0 = wm * 128 + mh * 64 + (lane & 15);
#pragma unroll
        for (int i = 0; i < 4; ++i) {
          int byte = (r0 + i * 16) * 64 + kb;
          byte = SWZ(byte);
          af[i] = *(const short8*)((const char*)Ah + byte);
        }
        if (mh == 0) {
          const short* Bh = Bb(buf, ks);
          const int c0 = wn * 64 + (lane & 15);
#pragma unroll
          for (int j = 0; j < 4; ++j) {
            int byte = (c0 + j * 16) * 64 + kb;
            byte = SWZ(byte);
            bf[j] = *(const short8*)((const char*)Bh + byte);
          }
        }
      }
      { const int h = 4 * t + p + 7; if (h < 4 * NT) stage(h); }
      SBAR();
      WAITL0();
      __builtin_amdgcn_s_setprio(1);
#pragma unroll
      for (int i = 0; i < 4; ++i)
#pragma unroll
        for (int j = 0; j < 4; ++j)
          acc[mh * 4 + i][j] = __builtin_amdgcn_mfma_f32_16x16x32_bf16(
              af[i], bf[j], acc[mh * 4 + i][j], 0, 0, 0);
      __builtin_amdgcn_s_setprio(0);
      if (p == 3) {
        if (t < NT - 2) {
          asm volatile("s_waitcnt vmcnt(6)" ::: "memory");
        } else if (t == NT - 2) {
          asm volatile("s_waitcnt vmcnt(0)" ::: "memory");
        }
      }
      SBAR();
    }
  }

  // epilogue: C/D layout col = lane&15, row = (lane>>4)*4 + reg
  const int rl = (lane >> 4) << 2;
#pragma unroll
  for (int f = 0; f < 8; ++f) {
    const int rbase = m0 + wm * 128 + f * 16 + rl;
#pragma unroll
    for (int j = 0; j < 4; ++j) {
      const int col = n0 + wn * 64 + j * 16 + (lane & 15);
      f32x4 a = acc[f][j];
      if constexpr (EPI == 0) {
        short* cp = Cb + (long)bz * cBatch;
#pragma unroll
        for (int r = 0; r < 4; ++r)
          cp[(long)(rbase + r) * N + col] = (short)f2bf(a[r]);
      } else if constexpr (EPI == 4) {
        const int pidx = col >> 10;
        const int dcol = col & (DM - 1);
        short* Cp = (pidx == 0) ? Cb : ((pidx == 1) ? Cb2 : Cb3);
        const float* bp = (pidx == 0) ? bias : ((pidx == 1) ? bias2 : bias3);
        const float bi = bp[dcol] * (bsc ? bsc[0] : 1.f);
#pragma unroll
        for (int r = 0; r < 4; ++r)
          Cp[(long)(rbase + r) * DM + dcol] = (short)f2bf(a[r] + bi);
      } else {
        float bi = bias[col];
#pragma unroll
        for (int r = 0; r < 4; ++r) {
          long o = (long)(rbase + r) * N + col;
          Cf[o] = a[r] + bi + resid[o];
        }
      }
    }
  }
}

// ---------------- launch ----------------
extern "C" void kernel_launch(void* const* d_in, const int* in_sizes, int n_in,
                              void* d_out, int out_size, void* d_ws, size_t ws_size,
                              hipStream_t stream) {
  const float* x     = (const float*)d_in[0];
  const float* fd    = (const float*)d_in[1];
  const float* Wq    = (const float*)d_in[2];
  const float* bq    = (const float*)d_in[3];
  const float* Wk    = (const float*)d_in[4];
  const float* bk    = (const float*)d_in[5];
  const float* Wv    = (const float*)d_in[6];
  const float* bv    = (const float*)d_in[7];
  const float* Wo    = (const float*)d_in[8];
  const float* bo    = (const float*)d_in[9];
  const float* alpha = (const float*)d_in[10];
  const float* fsc   = (const float*)d_in[11];
  float* out = (float*)d_out;

  // --- workspace layout (~112 MB) ---
  char* wp = (char*)d_ws;
  auto alloc = [&](size_t bytes) {
    char* p = wp;
    wp += (bytes + 255) & ~(size_t)255;
    return p;
  };
  float* cos_tab = (float*)alloc(S * 4);
  float* c_arr   = (float*)alloc(S * 4);          // c_arr[0] = c0 bias factor
  float* g       = (float*)alloc(S * 4);
  float* wsm     = (float*)alloc((size_t)NB * NH * S * 4);   // 1 MB
  short* WTcat = (short*)alloc((size_t)4 * DM * DM * 2);  // Wq,Wk,Wv,Wo transposed
  short* WoT   = WTcat + (size_t)3 * DM * DM;
  short* slotA = (short*)alloc((size_t)NB * DS * 2);  // ABout -> V
  short* slotB = (short*)alloc((size_t)NB * DS * 2);  // Ge/Go -> Mc2 + A2t
  short* slotC = (short*)alloc((size_t)NB * DS * 2);  // Xs -> att_half

  // d_out scratch phases: uv (34.6MB) during G-phase; Q,K during attention
  short* uv = (short*)d_out;                        // [8][DM][KH2]
  short* Qn = (short*)d_out;                        // [(b,s)][DM] 33.5 MB
  short* Kn = (short*)d_out + (size_t)NB * DS;      // [(b,s)][DM] 33.5 MB

  short* Ge  = slotB;                               // [2][MEO][KH2] (Ge,Go)
  short* ABout = slotA;                             // [8][MEO][DM]
  short* Xs  = slotC;
  short* Vn  = slotA;                               // V natural (after ABout dead)
  short* Mc2 = slotB;                               // 9.73 MB (after Ge dead)
  short* A2t = (short*)((char*)slotB + 10u * 1024 * 1024);
  short* att_half = slotC;

  dim3 blk(256), blk8(512);

  // tables, filter, even/odd matrices, fold, weights
  k_tables<<<dim3(S / 256), blk, 0, stream>>>(fd, alpha, fsc, cos_tab, c_arr);
  k_g<<<dim3(S / 16), blk, 0, stream>>>(cos_tab, c_arr, g);
  k_buildEO<<<dim3((unsigned)((long)MEO * KH2 / 8 / 256)), blk, 0, stream>>>(g, Ge);
  k_foldT<<<dim3(33, DM / 64, NB), blk, 0, stream>>>(x, uv);
  k_transW4<<<dim3(16, 16, 4), blk, 0, stream>>>(Wq, Wk, Wv, Wo, WTcat);

  // even/odd spectral GEMM: AB[z] = (z<4 ? Ge : Go) @ uv[z]; 256 wg
  dim3 geo(DM / 256, MEO / 256, 8);
  gemm8<0, 0, 1><<<geo, blk8, 0, stream>>>(Ge, uv, ABout, nullptr, nullptr, nullptr,
                                           nullptr, nullptr, nullptr, nullptr, nullptr,
                                           MEO, DM, KH2,
                                           (long)MEO * KH2, (long)DM * KH2, (long)MEO * DM);
  // unfold mirror + row n=2048 into Xs [b][s][d]
  k_unfold2<<<dim3(8192), blk, 0, stream>>>(ABout, g, uv, Xs);

  // fused q/k/v projections, natural output layout (EPI=4); Q,K -> d_out, V -> ws
  dim3 gqkv(3 * DM / 256, MTOT / 256, 1);   // (12,64,1) = 768 wg
  gemm8<4><<<gqkv, blk8, 0, stream>>>(Xs, WTcat, Qn, Kn, Vn, nullptr,
                                      bq, bk, bv, c_arr, nullptr,
                                      MTOT, 3 * DM, DM, 0, 0, 0);

  // fused logits + head-softmax, then fused attend + fold (tiled transpose)
  k_logsoft<<<dim3(MTOT / 16), blk, 0, stream>>>(Qn, Kn, wsm);
  k_attfold2<<<dim3(KH / 64, DM / 64, NB), blk, 0, stream>>>(Vn, wsm, A2t);

  // half-cos matrix, att_time_half = Mc2 @ A2
  k_buildM2<<<dim3((unsigned)((long)MH * KH / 8 / 256)), blk, 0, stream>>>(cos_tab, Mc2);
  dim3 ghalf(DM / 256, MH / 256, NB);
  gemm8<0><<<ghalf, blk8, 0, stream>>>(Mc2, A2t, att_half, nullptr, nullptr, nullptr,
                                       nullptr, nullptr, nullptr, nullptr, nullptr,
                                       MH, DM, KH, 0, (long)DM * KH, (long)MH * DM);

  // out = att_time @ Wo + bo + x  (A rows via mirror; fp32 epilogue)
  dim3 gproj(DM / 256, MTOT / 256, 1);
  gemm8<2, 1><<<gproj, blk8, 0, stream>>>(att_half, WoT, nullptr, nullptr, nullptr, out,
                                          bo, nullptr, nullptr, nullptr, x,
                                          MTOT, DM, DM, 0, 0, 0);
}

// Round 12
// 408.853 us; speedup vs baseline: 1.1516x; 1.0045x over previous
//
#include <hip/hip_runtime.h>

// ---------------- constants ----------------
#define S      4096
#define DM     1024
#define NB     4
#define NH     16
#define HDIM   64
#define MTOT   (NB * S)          // 16384
#define DS     ((long)DM * S)    // 4,194,304
#define MH     2304              // padded half-rows for Mc2 (2049 used)
#define KH     2112              // folded K for Mc2 (2049 used)
#define KH2    2112              // folded K for even/odd G split (2049 used)
#define MEO    2048              // even/odd GEMM rows (n=0..2047; n=2048 special)

typedef __attribute__((ext_vector_type(8))) short short8;
typedef __attribute__((ext_vector_type(4))) float f32x4;
typedef __attribute__((ext_vector_type(8))) unsigned short u16x8;
typedef __attribute__((ext_vector_type(4))) unsigned short u16x4;

__device__ __forceinline__ unsigned short f2bf(float f) {
  union { float f; unsigned u; } v; v.f = f;
  unsigned r = v.u + 0x7fffu + ((v.u >> 16) & 1u);   // RNE
  return (unsigned short)(r >> 16);
}
__device__ __forceinline__ float bf2f(short h) {
  union { unsigned u; float f; } v; v.u = ((unsigned)(unsigned short)h) << 16;
  return v.f;
}

#define GLOAD(gp, lp) __builtin_amdgcn_global_load_lds( \
    (const __attribute__((address_space(1))) void*)(gp), \
    (__attribute__((address_space(3))) void*)(lp), 16, 0, 0)

#define SBAR() do { asm volatile("" ::: "memory"); __builtin_amdgcn_s_barrier(); \
                    asm volatile("" ::: "memory"); } while (0)
#define WAITL0() asm volatile("s_waitcnt lgkmcnt(0)" ::: "memory")

// LDS swizzle for 64B-row tiles: XOR byte bits 4-5 with row bits 1-2 (byte bits 7-8).
#define SWZ(o) ((o) ^ ((((o) >> 7) & 3) << 4))

// ---------------- small kernels ----------------

__global__ void k_tables(const float* __restrict__ fd, const float* __restrict__ alpha,
                         const float* __restrict__ fsc,
                         float* __restrict__ cos_tab, float* __restrict__ c_arr) {
  int k = blockIdx.x * 256 + threadIdx.x;
  if (k >= S) return;
  float aa = alpha[0] + fsc[0] * (fd[0] - 1.5f);
  const float twopi = 6.28318530717958647692f;
  cos_tab[k] = cosf(twopi * ((float)k / (float)S));
  int kk = (k <= S / 2) ? k : (S - k);
  float af = (float)kk / (float)S;
  c_arr[k] = cosf(aa * atanf(logf(af + 1e-10f)));
}

// g[j] = (1/S) sum_k c[k] cos(2 pi j k / S); 16 lanes per j, deterministic reduce
__global__ void k_g(const float* __restrict__ cos_tab, const float* __restrict__ c_arr,
                    float* __restrict__ g) {
  __shared__ float sct[S];
  __shared__ float sc[S];
  __shared__ float red[16][17];
  for (int i = threadIdx.x; i < S; i += 256) { sct[i] = cos_tab[i]; sc[i] = c_arr[i]; }
  __syncthreads();
  int jl = threadIdx.x >> 4, r = threadIdx.x & 15;
  int j = blockIdx.x * 16 + jl;
  float acc = 0.f;
#pragma unroll 4
  for (int i = 0; i < 256; ++i) {
    int k = r + 16 * i;
    acc += sc[k] * sct[(j * k) & (S - 1)];
  }
  red[jl][r] = acc;
  __syncthreads();
  if (r == 0) {
    float s = 0.f;
#pragma unroll
    for (int i = 0; i < 16; ++i) s += red[jl][i];
    g[j] = s * (1.f / (float)S);
  }
}

// Ge/Go [MEO][KH2] bf16, Go at offset MEO*KH2.
__global__ void k_buildEO(const float* __restrict__ g, short* __restrict__ Ge) {
  long i8 = ((long)blockIdx.x * 256 + threadIdx.x) * 8;
  if (i8 >= (long)MEO * KH2) return;
  int n = (int)(i8 / KH2);
  int m = (int)(i8 % KH2);
  u16x8 ev, ov;
#pragma unroll
  for (int j = 0; j < 8; ++j) {
    int mm = m + j;
    float e, o;
    if (mm == 0)            { e = g[n]; o = 0.f; }
    else if (mm == 2048)    { e = g[(n + 2048) & (S - 1)]; o = 0.f; }
    else if (mm > 2048)     { e = 0.f; o = 0.f; }
    else {
      float a = g[(n - mm) & (S - 1)], b = g[(n + mm) & (S - 1)];
      e = 0.5f * (a + b); o = 0.5f * (a - b);
    }
    ev[j] = f2bf(e); ov[j] = f2bf(o);
  }
  *(u16x8*)(Ge + i8) = ev;
  *(u16x8*)(Ge + (long)MEO * KH2 + i8) = ov;
}

// fold x into u,v (transposed): uv[b][d][m] = x[b][m][d] +/- x[b][4096-m][d]
__global__ void k_foldT(const float* __restrict__ x, short* __restrict__ uv) {
  __shared__ float tp[64][65];
  __shared__ float tm[64][65];
  int m0 = blockIdx.x * 64, d0 = blockIdx.y * 64, b = blockIdx.z;
  int t = threadIdx.x;
  int r = t >> 4, c4 = (t & 15) * 4;
#pragma unroll
  for (int rr = 0; rr < 4; ++rr) {
    int m = m0 + r + rr * 16;
    float4 vp = *(const float4*)(x + ((long)(b * S + m)) * DM + d0 + c4);
    int ms = (S - m) & (S - 1);
    float4 vm = *(const float4*)(x + ((long)(b * S + ms)) * DM + d0 + c4);
    tp[r + rr * 16][c4 + 0] = vp.x; tp[r + rr * 16][c4 + 1] = vp.y;
    tp[r + rr * 16][c4 + 2] = vp.z; tp[r + rr * 16][c4 + 3] = vp.w;
    tm[r + rr * 16][c4 + 0] = vm.x; tm[r + rr * 16][c4 + 1] = vm.y;
    tm[r + rr * 16][c4 + 2] = vm.z; tm[r + rr * 16][c4 + 3] = vm.w;
  }
  __syncthreads();
  int m_loc = t & 63, dq = t >> 6;
#pragma unroll
  for (int i = 0; i < 16; ++i) {
    int d_loc = dq * 16 + i;
    int m = m0 + m_loc;
    float P = tp[m_loc][d_loc], M = tm[m_loc][d_loc];
    float u, v;
    if (m == 0 || m == 2048) { u = P; v = 0.f; }
    else if (m > 2048)       { u = 0.f; v = 0.f; }
    else                     { u = P + M; v = P - M; }
    long base = ((long)(b * DM + d0 + d_loc)) * KH2 + m;
    uv[base] = (short)f2bf(u);
    uv[base + (long)4 * DM * KH2] = (short)f2bf(v);
  }
}

// merged: blocks [0,4096): unfold AB -> Xs; blocks [4096,8192): row n=2048 dot
__global__ void k_unfold2(const short* __restrict__ AB, const float* __restrict__ g,
                          const short* __restrict__ uv, short* __restrict__ Xs) {
  __shared__ float red[256];
  int bx = blockIdx.x;
  if (bx < 4096) {
    long i8 = ((long)bx * 256 + threadIdx.x) * 8;
    int b = (int)(i8 >> 21);             // MEO*DM = 2^21
    long rr = i8 & ((1L << 21) - 1);
    int n = (int)(rr >> 10);
    int d = (int)(rr & (DM - 1));
    u16x8 av = *(const u16x8*)(AB + i8);
    u16x8 bv = *(const u16x8*)(AB + ((long)4 * MEO * DM) + i8);
    u16x8 sv, dv;
#pragma unroll
    for (int j = 0; j < 8; ++j) {
      float A = bf2f((short)av[j]), B = bf2f((short)bv[j]);
      sv[j] = f2bf(A + B);
      dv[j] = f2bf(A - B);
    }
    *(u16x8*)(Xs + ((long)b * S + n) * DM + d) = sv;
    if (n > 0)
      *(u16x8*)(Xs + ((long)b * S + (S - n)) * DM + d) = dv;
  } else {
    int bd = bx - 4096;                  // 0..NB*DM-1
    int b = bd >> 10, d = bd & (DM - 1);
    const short* up = uv + ((long)(b * DM + d)) * KH2;
    int t = threadIdx.x;
    float acc = 0.f;
    for (int m = t; m <= 2048; m += 256)
      acc += g[2048 - m] * bf2f(up[m]);
    red[t] = acc;
    __syncthreads();
    for (int sh = 128; sh > 0; sh >>= 1) {
      if (t < sh) red[t] += red[t + sh];
      __syncthreads();
    }
    if (t == 0) Xs[((long)b * S + 2048) * DM + d] = (short)f2bf(red[0]);
  }
}

// Mc2[n][m] (n<MH, m<KH, ld KH): (m<=2048) ? cos(2*pi*n*m/S)/64 : 0
__global__ void k_buildM2(const float* __restrict__ cos_tab, short* __restrict__ Mc2) {
  long i8 = ((long)blockIdx.x * 256 + threadIdx.x) * 8;
  if (i8 >= (long)MH * KH) return;
  int n = (int)(i8 / KH);
  int m = (int)(i8 % KH);
  u16x8 mv;
#pragma unroll
  for (int j = 0; j < 8; ++j) {
    int mm = m + j;
    float vv = (mm <= 2048) ? cos_tab[(n * mm) & (S - 1)] * 0.015625f : 0.f;
    mv[j] = f2bf(vv);
  }
  *(u16x8*)(Mc2 + i8) = mv;
}

// all 4 weights: W[z] [K][N] fp32 -> WT + z*DM*DM as [N][K] bf16
__global__ void k_transW4(const float* __restrict__ W0, const float* __restrict__ W1,
                          const float* __restrict__ W2, const float* __restrict__ W3,
                          short* __restrict__ WT) {
  __shared__ float tile[64][65];
  int z = blockIdx.z;
  const float* W = (z == 0) ? W0 : ((z == 1) ? W1 : ((z == 2) ? W2 : W3));
  short* WTo = WT + (size_t)z * DM * DM;
  int k0 = blockIdx.x * 64, n0 = blockIdx.y * 64;
  int t = threadIdx.x;
  int r = t >> 4, c4 = (t & 15) * 4;
  const float* ip = W + (long)k0 * DM + n0;
#pragma unroll
  for (int rr = 0; rr < 4; ++rr) {
    float4 v = *(const float4*)(ip + (long)(r + rr * 16) * DM + c4);
    tile[r + rr * 16][c4 + 0] = v.x;
    tile[r + rr * 16][c4 + 1] = v.y;
    tile[r + rr * 16][c4 + 2] = v.z;
    tile[r + rr * 16][c4 + 3] = v.w;
  }
  __syncthreads();
  int k_loc = t & 63, nq = t >> 6;
  short* op = WTo + (long)n0 * DM + k0;
#pragma unroll
  for (int i = 0; i < 16; ++i) {
    int n_loc = nq * 16 + i;
    op[(long)n_loc * DM + k_loc] = (short)f2bf(tile[k_loc][n_loc]);
  }
}

// fused logits+head-softmax. Q,K in natural [(b,s)][DM] layout.
__global__ void k_logsoft(const short* __restrict__ Q, const short* __restrict__ K,
                          float* __restrict__ w) {
  int idx = blockIdx.x * 16 + (threadIdx.x >> 4);   // (b,s) 0..16383
  int h = threadIdx.x & 15;
  const short* q = Q + (long)idx * DM + h * HDIM;
  const short* k = K + (long)idx * DM + h * HDIM;
  float acc = 0.f;
#pragma unroll
  for (int jj = 0; jj < 8; ++jj) {
    u16x8 qa = *(const u16x8*)(q + jj * 8);
    u16x8 ka = *(const u16x8*)(k + jj * 8);
#pragma unroll
    for (int l = 0; l < 8; ++l) acc += bf2f((short)qa[l]) * bf2f((short)ka[l]);
  }
  acc *= 0.125f;
  float m = acc;
#pragma unroll
  for (int d = 1; d < 16; d <<= 1) m = fmaxf(m, __shfl_xor(m, d, 16));
  float e = expf(acc - m);
  float ssum = e;
#pragma unroll
  for (int d = 1; d < 16; d <<= 1) ssum += __shfl_xor(ssum, d, 16);
  int b = idx >> 12, s = idx & (S - 1);
  w[((long)b * NH + h) * S + s] = e / ssum;
}

// fused attend+fold, tiled transpose. V natural [(b,s)][DM] -> A2t[b][d][m].
__global__ void k_attfold2(const short* __restrict__ V, const float* __restrict__ wsm,
                           short* __restrict__ A2t) {
  __shared__ float t1[64][65];
  __shared__ float t2[64][65];
  __shared__ float w1[64], w2[64];
  int m0 = blockIdx.x * 64, d0 = blockIdx.y * 64, b = blockIdx.z;
  int t = threadIdx.x;
  int h0 = d0 >> 6;
  if (t < 64) {
    int m = m0 + t;
    const float* wp = wsm + ((long)b * NH + h0) * S;
    w1[t] = wp[m & (S - 1)];
    w2[t] = wp[(S - m) & (S - 1)];
  }
  int r = t >> 4, c4 = (t & 15) * 4;
#pragma unroll
  for (int rr = 0; rr < 4; ++rr) {
    int i = r + rr * 16;
    int m = m0 + i;
    u16x4 a = *(const u16x4*)(V + ((long)(b * S + (m & (S - 1)))) * DM + d0 + c4);
    u16x4 bb = *(const u16x4*)(V + ((long)(b * S + ((S - m) & (S - 1)))) * DM + d0 + c4);
#pragma unroll
    for (int l = 0; l < 4; ++l) {
      t1[i][c4 + l] = bf2f((short)a[l]);
      t2[i][c4 + l] = bf2f((short)bb[l]);
    }
  }
  __syncthreads();
  int i_loc = t & 63, jq = t >> 6;
  int m = m0 + i_loc;
#pragma unroll
  for (int jj = 0; jj < 16; ++jj) {
    int j = jq * 16 + jj;
    float rv;
    if (m == 0 || m == 2048) rv = w1[i_loc] * t1[i_loc][j];
    else if (m < 2048)       rv = w1[i_loc] * t1[i_loc][j] + w2[i_loc] * t2[i_loc][j];
    else                     rv = 0.f;
    A2t[((long)(b * DM + d0 + j)) * KH + m] = (short)f2bf(rv);
  }
}

// ---------------- 256x256 8-phase GEMM ----------------
// C = A @ B ; A row-major [M,K] bf16, B TRANSPOSED as Bt [N,K] bf16, ld = K.
// AMIR: A rows via even-symmetry mirror (att_time_half).
// ASEL: A base = A + (bz>>2)*aBatch (even/odd matrix pair), B/C batched by bz.
// WALK: 0 = n-fastest wg walk; 1 = m-fastest.
// MREP: persistent-wg — each block processes MREP logical tiles (tile = swz +
//       rep*nwg); cuts per-block launch/teardown/prologue fixed cost for
//       multi-round dispatches (1 resident block/CU at 128KB LDS).
// EPI 0: bf16 C[M,N] per-batch.  EPI 2: fp32 C + bias + resid.
// EPI 4: QKV natural layout — rows=(b,s), col=dout; Cb/Cb2/Cb3 by col>>10.
template <int EPI, int AMIR = 0, int ASEL = 0, int WALK = 0, int MREP = 1>
__global__ __launch_bounds__(512, 2) void gemm8(
    const short* __restrict__ A, const short* __restrict__ Bt,
    short* __restrict__ Cb, short* __restrict__ Cb2, short* __restrict__ Cb3,
    float* __restrict__ Cf,
    const float* __restrict__ bias, const float* __restrict__ bias2,
    const float* __restrict__ bias3,
    const float* __restrict__ bsc, const float* __restrict__ resid,
    int M, int N, int K, long aBatch, long bBatch, long cBatch) {
  __shared__ __align__(16) short SH[65536];   // 128 KiB: A halves then B halves
  auto Ab = [&](int buf, int ks) { return SH + (buf * 2 + ks) * 8192; };
  auto Bb = [&](int buf, int ks) { return SH + 32768 + (buf * 2 + ks) * 8192; };

  // bijective XCD-chunked remap (nwg % 8 == 0 in all our launches)
  const int gx = gridDim.x, gy = gridDim.y;
  const int nwg = gx * gy * gridDim.z;
  int lin = blockIdx.x + gx * (blockIdx.y + gy * blockIdx.z);
  int swz = lin;
  if ((nwg & 7) == 0) {
    const int cpx = nwg >> 3;
    swz = (lin & 7) * cpx + (lin >> 3);
  }
  const int NTN = N >> 8;
  const int NTM = M >> 8;
  const int tid = threadIdx.x;
  const int lane = tid & 63;
  const int wid = tid >> 6;
  const int wm = wid >> 2, wn = wid & 3;

  for (int rep = 0; rep < MREP; ++rep) {
    const int wg = swz + rep * nwg;
    int ntile, mtile, bz;
    if (WALK) {
      mtile = wg % NTM;
      const int rest = wg / NTM;
      ntile = rest % NTN;
      bz = rest / NTN;
    } else {
      ntile = wg % NTN;
      const int rest = wg / NTN;
      mtile = rest % NTM;
      bz = rest / NTM;
    }

    const short* Ag = ASEL ? (A + (long)(bz >> 2) * aBatch) : (A + (long)bz * aBatch);
    const short* Bg = Bt + (long)bz * bBatch;
    const int m0 = mtile << 8, n0 = ntile << 8;

    f32x4 acc[8][4];
#pragma unroll
    for (int i = 0; i < 8; ++i)
#pragma unroll
      for (int j = 0; j < 4; ++j) acc[i][j] = (f32x4){0.f, 0.f, 0.f, 0.f};

    const int NT = K >> 6;
    auto stage = [&](int h) {
      const int tau = h >> 2, q = h & 3;
      const int buf = tau & 1, ks = q >> 1;
      short* ldsbase = (q & 1) ? Bb(buf, ks) : Ab(buf, ks);
      const short* gsrc = (q & 1) ? Bg : Ag;
      const int row0 = (q & 1) ? n0 : m0;
      const long k0 = (long)tau * 64 + ks * 32;
#pragma unroll
      for (int j = 0; j < 2; ++j) {
        const int o = tid * 16 + j * 8192;
        const int lo = SWZ(o);
        const int row = lo >> 6;
        const int cs = (lo & 63) >> 1;
        const short* gp;
        if (AMIR && !(q & 1)) {
          int grow = row0 + row;
          int b_ = grow >> 12, s_ = grow & (S - 1);
          int sm = (s_ <= 2048) ? s_ : (4096 - s_);
          gp = Ag + ((long)b_ * MH + sm) * K + k0 + cs;
        } else {
          gp = gsrc + (long)(row0 + row) * K + k0 + cs;
        }
        GLOAD(gp, (short*)((char*)ldsbase + o));
      }
    };

    if (rep > 0) SBAR();   // previous rep's LDS reads long done; order stage writes
    for (int h = 0; h < 7; ++h) stage(h);
    asm volatile("s_waitcnt vmcnt(6)" ::: "memory");
    SBAR();

    short8 bf[4];
    for (int t = 0; t < NT; ++t) {
      const int buf = t & 1;
#pragma unroll
      for (int p = 0; p < 4; ++p) {
        const int ks = p >> 1, mh = p & 1;
        short8 af[4];
        {
          const short* Ah = Ab(buf, ks);
          const int kb = (lane >> 4) * 16;
          const int r0 = wm * 128 + mh * 64 + (lane & 15);
#pragma unroll
          for (int i = 0; i < 4; ++i) {
            int byte = (r0 + i * 16) * 64 + kb;
            byte = SWZ(byte);
            af[i] = *(const short8*)((const char*)Ah + byte);
          }
          if (mh == 0) {
            const short* Bh = Bb(buf, ks);
            const int c0 = wn * 64 + (lane & 15);
#pragma unroll
            for (int j = 0; j < 4; ++j) {
              int byte = (c0 + j * 16) * 64 + kb;
              byte = SWZ(byte);
              bf[j] = *(const short8*)((const char*)Bh + byte);
            }
          }
        }
        { const int h = 4 * t + p + 7; if (h < 4 * NT) stage(h); }
        SBAR();
        WAITL0();
        __builtin_amdgcn_s_setprio(1);
#pragma unroll
        for (int i = 0; i < 4; ++i)
#pragma unroll
          for (int j = 0; j < 4; ++j)
            acc[mh * 4 + i][j] = __builtin_amdgcn_mfma_f32_16x16x32_bf16(
                af[i], bf[j], acc[mh * 4 + i][j], 0, 0, 0);
        __builtin_amdgcn_s_setprio(0);
        if (p == 3) {
          if (t < NT - 2) {
            asm volatile("s_waitcnt vmcnt(6)" ::: "memory");
          } else if (t == NT - 2) {
            asm volatile("s_waitcnt vmcnt(0)" ::: "memory");
          }
        }
        SBAR();
      }
    }

    // epilogue: C/D layout col = lane&15, row = (lane>>4)*4 + reg
    const int rl = (lane >> 4) << 2;
#pragma unroll
    for (int f = 0; f < 8; ++f) {
      const int rbase = m0 + wm * 128 + f * 16 + rl;
#pragma unroll
      for (int j = 0; j < 4; ++j) {
        const int col = n0 + wn * 64 + j * 16 + (lane & 15);
        f32x4 a = acc[f][j];
        if constexpr (EPI == 0) {
          short* cp = Cb + (long)bz * cBatch;
#pragma unroll
          for (int r = 0; r < 4; ++r)
            cp[(long)(rbase + r) * N + col] = (short)f2bf(a[r]);
        } else if constexpr (EPI == 4) {
          const int pidx = col >> 10;
          const int dcol = col & (DM - 1);
          short* Cp = (pidx == 0) ? Cb : ((pidx == 1) ? Cb2 : Cb3);
          const float* bp = (pidx == 0) ? bias : ((pidx == 1) ? bias2 : bias3);
          const float bi = bp[dcol] * (bsc ? bsc[0] : 1.f);
#pragma unroll
          for (int r = 0; r < 4; ++r)
            Cp[(long)(rbase + r) * DM + dcol] = (short)f2bf(a[r] + bi);
        } else {
          float bi = bias[col];
#pragma unroll
          for (int r = 0; r < 4; ++r) {
            long o = (long)(rbase + r) * N + col;
            Cf[o] = a[r] + bi + resid[o];
          }
        }
      }
    }
  }
}

// ---------------- launch ----------------
extern "C" void kernel_launch(void* const* d_in, const int* in_sizes, int n_in,
                              void* d_out, int out_size, void* d_ws, size_t ws_size,
                              hipStream_t stream) {
  const float* x     = (const float*)d_in[0];
  const float* fd    = (const float*)d_in[1];
  const float* Wq    = (const float*)d_in[2];
  const float* bq    = (const float*)d_in[3];
  const float* Wk    = (const float*)d_in[4];
  const float* bk    = (const float*)d_in[5];
  const float* Wv    = (const float*)d_in[6];
  const float* bv    = (const float*)d_in[7];
  const float* Wo    = (const float*)d_in[8];
  const float* bo    = (const float*)d_in[9];
  const float* alpha = (const float*)d_in[10];
  const float* fsc   = (const float*)d_in[11];
  float* out = (float*)d_out;

  // --- workspace layout (~112 MB) ---
  char* wp = (char*)d_ws;
  auto alloc = [&](size_t bytes) {
    char* p = wp;
    wp += (bytes + 255) & ~(size_t)255;
    return p;
  };
  float* cos_tab = (float*)alloc(S * 4);
  float* c_arr   = (float*)alloc(S * 4);          // c_arr[0] = c0 bias factor
  float* g       = (float*)alloc(S * 4);
  float* wsm     = (float*)alloc((size_t)NB * NH * S * 4);   // 1 MB
  short* WTcat = (short*)alloc((size_t)4 * DM * DM * 2);  // Wq,Wk,Wv,Wo transposed
  short* WoT   = WTcat + (size_t)3 * DM * DM;
  short* slotA = (short*)alloc((size_t)NB * DS * 2);  // ABout -> V
  short* slotB = (short*)alloc((size_t)NB * DS * 2);  // Ge/Go -> Mc2 + A2t
  short* slotC = (short*)alloc((size_t)NB * DS * 2);  // Xs -> att_half

  // d_out scratch phases: uv (34.6MB) during G-phase; Q,K during attention
  short* uv = (short*)d_out;                        // [8][DM][KH2]
  short* Qn = (short*)d_out;                        // [(b,s)][DM] 33.5 MB
  short* Kn = (short*)d_out + (size_t)NB * DS;      // [(b,s)][DM] 33.5 MB

  short* Ge  = slotB;                               // [2][MEO][KH2] (Ge,Go)
  short* ABout = slotA;                             // [8][MEO][DM]
  short* Xs  = slotC;
  short* Vn  = slotA;                               // V natural (after ABout dead)
  short* Mc2 = slotB;                               // 9.73 MB (after Ge dead)
  short* A2t = (short*)((char*)slotB + 10u * 1024 * 1024);
  short* att_half = slotC;

  dim3 blk(256), blk8(512);

  // tables, filter, even/odd matrices, fold, weights
  k_tables<<<dim3(S / 256), blk, 0, stream>>>(fd, alpha, fsc, cos_tab, c_arr);
  k_g<<<dim3(S / 16), blk, 0, stream>>>(cos_tab, c_arr, g);
  k_buildEO<<<dim3((unsigned)((long)MEO * KH2 / 8 / 256)), blk, 0, stream>>>(g, Ge);
  k_foldT<<<dim3(33, DM / 64, NB), blk, 0, stream>>>(x, uv);
  k_transW4<<<dim3(16, 16, 4), blk, 0, stream>>>(Wq, Wk, Wv, Wo, WTcat);

  // even/odd spectral GEMM: AB[z] = (z<4 ? Ge : Go) @ uv[z]; 256 wg
  dim3 geo(DM / 256, MEO / 256, 8);
  gemm8<0, 0, 1><<<geo, blk8, 0, stream>>>(Ge, uv, ABout, nullptr, nullptr, nullptr,
                                           nullptr, nullptr, nullptr, nullptr, nullptr,
                                           MEO, DM, KH2,
                                           (long)MEO * KH2, (long)DM * KH2, (long)MEO * DM);
  // unfold mirror + row n=2048 into Xs [b][s][d]
  k_unfold2<<<dim3(8192), blk, 0, stream>>>(ABout, g, uv, Xs);

  // fused q/k/v projections, natural output layout (EPI=4), persistent-wg:
  // 256 blocks x 3 logical tiles each (was 768 blocks / 3 serial rounds per CU)
  gemm8<4, 0, 0, 0, 3><<<dim3(256), blk8, 0, stream>>>(
      Xs, WTcat, Qn, Kn, Vn, nullptr, bq, bk, bv, c_arr, nullptr,
      MTOT, 3 * DM, DM, 0, 0, 0);

  // fused logits + head-softmax, then fused attend + fold (tiled transpose)
  k_logsoft<<<dim3(MTOT / 16), blk, 0, stream>>>(Qn, Kn, wsm);
  k_attfold2<<<dim3(KH / 64, DM / 64, NB), blk, 0, stream>>>(Vn, wsm, A2t);

  // half-cos matrix, att_time_half = Mc2 @ A2
  k_buildM2<<<dim3((unsigned)((long)MH * KH / 8 / 256)), blk, 0, stream>>>(cos_tab, Mc2);
  dim3 ghalf(DM / 256, MH / 256, NB);
  gemm8<0><<<ghalf, blk8, 0, stream>>>(Mc2, A2t, att_half, nullptr, nullptr, nullptr,
                                       nullptr, nullptr, nullptr, nullptr, nullptr,
                                       MH, DM, KH, 0, (long)DM * KH, (long)MH * DM);

  // out = att_time @ Wo + bo + x  (A rows via mirror; fp32 epilogue)
  dim3 gproj(DM / 256, MTOT / 256, 1);
  gemm8<2, 1><<<gproj, blk8, 0, stream>>>(att_half, WoT, nullptr, nullptr, nullptr, out,
                                          bo, nullptr, nullptr, nullptr, x,
                                          MTOT, DM, DM, 0, 0, 0);
}

// Round 13
// 388.989 us; speedup vs baseline: 1.2104x; 1.0511x over previous
//
#include <hip/hip_runtime.h>

// ---------------- constants ----------------
#define S      4096
#define DM     1024
#define NB     4
#define NH     16
#define HDIM   64
#define MTOT   (NB * S)          // 16384
#define DS     ((long)DM * S)    // 4,194,304
#define MH     2304              // padded half-rows for Mc2 (2049 used)
#define KH     2112              // folded K for Mc2 (2049 used)
#define KH2    2112              // folded K for even/odd G split (2049 used)
#define MEO    2048              // even/odd GEMM rows (n=0..2047; n=2048 special)

typedef __attribute__((ext_vector_type(8))) short short8;
typedef __attribute__((ext_vector_type(4))) float f32x4;
typedef __attribute__((ext_vector_type(8))) unsigned short u16x8;
typedef __attribute__((ext_vector_type(4))) unsigned short u16x4;

__device__ __forceinline__ unsigned short f2bf(float f) {
  union { float f; unsigned u; } v; v.f = f;
  unsigned r = v.u + 0x7fffu + ((v.u >> 16) & 1u);   // RNE
  return (unsigned short)(r >> 16);
}
__device__ __forceinline__ float bf2f(short h) {
  union { unsigned u; float f; } v; v.u = ((unsigned)(unsigned short)h) << 16;
  return v.f;
}

#define GLOAD(gp, lp) __builtin_amdgcn_global_load_lds( \
    (const __attribute__((address_space(1))) void*)(gp), \
    (__attribute__((address_space(3))) void*)(lp), 16, 0, 0)

#define SBAR() do { asm volatile("" ::: "memory"); __builtin_amdgcn_s_barrier(); \
                    asm volatile("" ::: "memory"); } while (0)
#define WAITL0() asm volatile("s_waitcnt lgkmcnt(0)" ::: "memory")

// LDS swizzle for 64B-row tiles: XOR byte bits 4-5 with row bits 1-2 (byte bits 7-8).
#define SWZ(o) ((o) ^ ((((o) >> 7) & 3) << 4))

// ---------------- small kernels ----------------

// merged tables + g. Blocks 0-15: write cos_tab/c_arr (for buildM2/buildEO
// consumers). Blocks 16-271: compute g[j] with block-local tables (identical
// fp formulas -> identical values, deterministic).
__global__ void k_tabg(const float* __restrict__ fd, const float* __restrict__ alpha,
                       const float* __restrict__ fsc,
                       float* __restrict__ cos_tab, float* __restrict__ c_arr,
                       float* __restrict__ g) {
  const float twopi = 6.28318530717958647692f;
  float aa = alpha[0] + fsc[0] * (fd[0] - 1.5f);
  int bx = blockIdx.x;
  if (bx < 16) {
    int k = bx * 256 + threadIdx.x;
    cos_tab[k] = cosf(twopi * ((float)k / (float)S));
    int kk = (k <= S / 2) ? k : (S - k);
    float af = (float)kk / (float)S;
    c_arr[k] = cosf(aa * atanf(logf(af + 1e-10f)));
    return;
  }
  __shared__ float sct[S];
  __shared__ float sc[S];
  __shared__ float red[16][17];
  for (int i = threadIdx.x; i < S; i += 256) {
    sct[i] = cosf(twopi * ((float)i / (float)S));
    int kk = (i <= S / 2) ? i : (S - i);
    float af = (float)kk / (float)S;
    sc[i] = cosf(aa * atanf(logf(af + 1e-10f)));
  }
  __syncthreads();
  int jl = threadIdx.x >> 4, r = threadIdx.x & 15;
  int j = (bx - 16) * 16 + jl;
  float acc = 0.f;
#pragma unroll 4
  for (int i = 0; i < 256; ++i) {
    int k = r + 16 * i;
    acc += sc[k] * sct[(j * k) & (S - 1)];
  }
  red[jl][r] = acc;
  __syncthreads();
  if (r == 0) {
    float s = 0.f;
#pragma unroll
    for (int i = 0; i < 16; ++i) s += red[jl][i];
    g[j] = s * (1.f / (float)S);
  }
}

// Ge/Go [MEO][KH2] bf16, Go at offset MEO*KH2.
__global__ void k_buildEO(const float* __restrict__ g, short* __restrict__ Ge) {
  long i8 = ((long)blockIdx.x * 256 + threadIdx.x) * 8;
  if (i8 >= (long)MEO * KH2) return;
  int n = (int)(i8 / KH2);
  int m = (int)(i8 % KH2);
  u16x8 ev, ov;
#pragma unroll
  for (int j = 0; j < 8; ++j) {
    int mm = m + j;
    float e, o;
    if (mm == 0)            { e = g[n]; o = 0.f; }
    else if (mm == 2048)    { e = g[(n + 2048) & (S - 1)]; o = 0.f; }
    else if (mm > 2048)     { e = 0.f; o = 0.f; }
    else {
      float a = g[(n - mm) & (S - 1)], b = g[(n + mm) & (S - 1)];
      e = 0.5f * (a + b); o = 0.5f * (a - b);
    }
    ev[j] = f2bf(e); ov[j] = f2bf(o);
  }
  *(u16x8*)(Ge + i8) = ev;
  *(u16x8*)(Ge + (long)MEO * KH2 + i8) = ov;
}

// merged foldT + transW4. bx<33: fold x->uv tile; bx>=33: transpose weight bz.
__global__ void k_prep(const float* __restrict__ x, short* __restrict__ uv,
                       const float* __restrict__ W0, const float* __restrict__ W1,
                       const float* __restrict__ W2, const float* __restrict__ W3,
                       short* __restrict__ WT) {
  __shared__ float sh[2 * 64 * 65];
  int bx = blockIdx.x, by = blockIdx.y, bz = blockIdx.z;
  int t = threadIdx.x;
  int r = t >> 4, c4 = (t & 15) * 4;
  if (bx >= 33) {
    // transW for weight bz: tile (bx-33, by)
    float (*tile)[65] = (float(*)[65])sh;
    const float* W = (bz == 0) ? W0 : ((bz == 1) ? W1 : ((bz == 2) ? W2 : W3));
    short* WTo = WT + (size_t)bz * DM * DM;
    int k0 = (bx - 33) * 64, n0 = by * 64;
    const float* ip = W + (long)k0 * DM + n0;
#pragma unroll
    for (int rr = 0; rr < 4; ++rr) {
      float4 v = *(const float4*)(ip + (long)(r + rr * 16) * DM + c4);
      tile[r + rr * 16][c4 + 0] = v.x;
      tile[r + rr * 16][c4 + 1] = v.y;
      tile[r + rr * 16][c4 + 2] = v.z;
      tile[r + rr * 16][c4 + 3] = v.w;
    }
    __syncthreads();
    int k_loc = t & 63, nq = t >> 6;
    short* op = WTo + (long)n0 * DM + k0;
#pragma unroll
    for (int i = 0; i < 16; ++i) {
      int n_loc = nq * 16 + i;
      op[(long)n_loc * DM + k_loc] = (short)f2bf(tile[k_loc][n_loc]);
    }
    return;
  }
  // foldT tile
  float (*tp)[65] = (float(*)[65])sh;
  float (*tm)[65] = (float(*)[65])(sh + 64 * 65);
  int m0 = bx * 64, d0 = by * 64, b = bz;
#pragma unroll
  for (int rr = 0; rr < 4; ++rr) {
    int m = m0 + r + rr * 16;
    float4 vp = *(const float4*)(x + ((long)(b * S + m)) * DM + d0 + c4);
    int ms = (S - m) & (S - 1);
    float4 vm = *(const float4*)(x + ((long)(b * S + ms)) * DM + d0 + c4);
    tp[r + rr * 16][c4 + 0] = vp.x; tp[r + rr * 16][c4 + 1] = vp.y;
    tp[r + rr * 16][c4 + 2] = vp.z; tp[r + rr * 16][c4 + 3] = vp.w;
    tm[r + rr * 16][c4 + 0] = vm.x; tm[r + rr * 16][c4 + 1] = vm.y;
    tm[r + rr * 16][c4 + 2] = vm.z; tm[r + rr * 16][c4 + 3] = vm.w;
  }
  __syncthreads();
  int m_loc = t & 63, dq = t >> 6;
#pragma unroll
  for (int i = 0; i < 16; ++i) {
    int d_loc = dq * 16 + i;
    int m = m0 + m_loc;
    float P = tp[m_loc][d_loc], M = tm[m_loc][d_loc];
    float u, v;
    if (m == 0 || m == 2048) { u = P; v = 0.f; }
    else if (m > 2048)       { u = 0.f; v = 0.f; }
    else                     { u = P + M; v = P - M; }
    long base = ((long)(b * DM + d0 + d_loc)) * KH2 + m;
    uv[base] = (short)f2bf(u);
    uv[base + (long)4 * DM * KH2] = (short)f2bf(v);
  }
}

// merged: blocks [0,4096): unfold AB -> Xs; blocks [4096,8192): row n=2048 dot
__global__ void k_unfold2(const short* __restrict__ AB, const float* __restrict__ g,
                          const short* __restrict__ uv, short* __restrict__ Xs) {
  __shared__ float red[256];
  int bx = blockIdx.x;
  if (bx < 4096) {
    long i8 = ((long)bx * 256 + threadIdx.x) * 8;
    int b = (int)(i8 >> 21);             // MEO*DM = 2^21
    long rr = i8 & ((1L << 21) - 1);
    int n = (int)(rr >> 10);
    int d = (int)(rr & (DM - 1));
    u16x8 av = *(const u16x8*)(AB + i8);
    u16x8 bv = *(const u16x8*)(AB + ((long)4 * MEO * DM) + i8);
    u16x8 sv, dv;
#pragma unroll
    for (int j = 0; j < 8; ++j) {
      float A = bf2f((short)av[j]), B = bf2f((short)bv[j]);
      sv[j] = f2bf(A + B);
      dv[j] = f2bf(A - B);
    }
    *(u16x8*)(Xs + ((long)b * S + n) * DM + d) = sv;
    if (n > 0)
      *(u16x8*)(Xs + ((long)b * S + (S - n)) * DM + d) = dv;
  } else {
    int bd = bx - 4096;                  // 0..NB*DM-1
    int b = bd >> 10, d = bd & (DM - 1);
    const short* up = uv + ((long)(b * DM + d)) * KH2;
    int t = threadIdx.x;
    float acc = 0.f;
    for (int m = t; m <= 2048; m += 256)
      acc += g[2048 - m] * bf2f(up[m]);
    red[t] = acc;
    __syncthreads();
    for (int sh = 128; sh > 0; sh >>= 1) {
      if (t < sh) red[t] += red[t + sh];
      __syncthreads();
    }
    if (t == 0) Xs[((long)b * S + 2048) * DM + d] = (short)f2bf(red[0]);
  }
}

// fused logits+head-softmax. Q,K in natural [(b,s)][DM] layout.
__global__ void k_logsoft(const short* __restrict__ Q, const short* __restrict__ K,
                          float* __restrict__ w) {
  int idx = blockIdx.x * 16 + (threadIdx.x >> 4);   // (b,s) 0..16383
  int h = threadIdx.x & 15;
  const short* q = Q + (long)idx * DM + h * HDIM;
  const short* k = K + (long)idx * DM + h * HDIM;
  float acc = 0.f;
#pragma unroll
  for (int jj = 0; jj < 8; ++jj) {
    u16x8 qa = *(const u16x8*)(q + jj * 8);
    u16x8 ka = *(const u16x8*)(k + jj * 8);
#pragma unroll
    for (int l = 0; l < 8; ++l) acc += bf2f((short)qa[l]) * bf2f((short)ka[l]);
  }
  acc *= 0.125f;
  float m = acc;
#pragma unroll
  for (int d = 1; d < 16; d <<= 1) m = fmaxf(m, __shfl_xor(m, d, 16));
  float e = expf(acc - m);
  float ssum = e;
#pragma unroll
  for (int d = 1; d < 16; d <<= 1) ssum += __shfl_xor(ssum, d, 16);
  int b = idx >> 12, s = idx & (S - 1);
  w[((long)b * NH + h) * S + s] = e / ssum;
}

// merged attfold2 + buildM2. bx<33: attend+fold tile; bx>=33: buildM2 chunk.
__global__ void k_attfoldM2(const short* __restrict__ V, const float* __restrict__ wsm,
                            short* __restrict__ A2t,
                            const float* __restrict__ cos_tab, short* __restrict__ Mc2) {
  int bx = blockIdx.x, by = blockIdx.y, bz = blockIdx.z;
  if (bx >= 33) {
    long lin = (long)(bx - 33) + 38L * (by + 16L * bz);   // 0..2431
    long i8 = (lin * 256 + threadIdx.x) * 8;
    if (i8 >= (long)MH * KH) return;
    int n = (int)(i8 / KH);
    int m = (int)(i8 % KH);
    u16x8 mv;
#pragma unroll
    for (int j = 0; j < 8; ++j) {
      int mm = m + j;
      float vv = (mm <= 2048) ? cos_tab[(n * mm) & (S - 1)] * 0.015625f : 0.f;
      mv[j] = f2bf(vv);
    }
    *(u16x8*)(Mc2 + i8) = mv;
    return;
  }
  __shared__ float t1[64][65];
  __shared__ float t2[64][65];
  __shared__ float w1[64], w2[64];
  int m0 = bx * 64, d0 = by * 64, b = bz;
  int t = threadIdx.x;
  int h0 = d0 >> 6;
  if (t < 64) {
    int m = m0 + t;
    const float* wp = wsm + ((long)b * NH + h0) * S;
    w1[t] = wp[m & (S - 1)];
    w2[t] = wp[(S - m) & (S - 1)];
  }
  int r = t >> 4, c4 = (t & 15) * 4;
#pragma unroll
  for (int rr = 0; rr < 4; ++rr) {
    int i = r + rr * 16;
    int m = m0 + i;
    u16x4 a = *(const u16x4*)(V + ((long)(b * S + (m & (S - 1)))) * DM + d0 + c4);
    u16x4 bb = *(const u16x4*)(V + ((long)(b * S + ((S - m) & (S - 1)))) * DM + d0 + c4);
#pragma unroll
    for (int l = 0; l < 4; ++l) {
      t1[i][c4 + l] = bf2f((short)a[l]);
      t2[i][c4 + l] = bf2f((short)bb[l]);
    }
  }
  __syncthreads();
  int i_loc = t & 63, jq = t >> 6;
  int m = m0 + i_loc;
#pragma unroll
  for (int jj = 0; jj < 16; ++jj) {
    int j = jq * 16 + jj;
    float rv;
    if (m == 0 || m == 2048) rv = w1[i_loc] * t1[i_loc][j];
    else if (m < 2048)       rv = w1[i_loc] * t1[i_loc][j] + w2[i_loc] * t2[i_loc][j];
    else                     rv = 0.f;
    A2t[((long)(b * DM + d0 + j)) * KH + m] = (short)f2bf(rv);
  }
}

// ---------------- 256x256 8-phase GEMM ----------------
// C = A @ B ; A row-major [M,K] bf16, B TRANSPOSED as Bt [N,K] bf16, ld = K.
// AMIR: A rows via even-symmetry mirror (att_time_half).
// ASEL: A base = A + (bz>>2)*aBatch (even/odd matrix pair), B/C batched by bz.
// WALK: 0 = n-fastest wg walk; 1 = m-fastest.   MREP: persistent-wg reps.
// EPI 0: bf16 C[M,N] per-batch.  EPI 2: fp32 C + bias + resid.
// EPI 4: QKV natural layout — rows=(b,s), col=dout; Cb/Cb2/Cb3 by col>>10.
template <int EPI, int AMIR = 0, int ASEL = 0, int WALK = 0, int MREP = 1>
__global__ __launch_bounds__(512, 2) void gemm8(
    const short* __restrict__ A, const short* __restrict__ Bt,
    short* __restrict__ Cb, short* __restrict__ Cb2, short* __restrict__ Cb3,
    float* __restrict__ Cf,
    const float* __restrict__ bias, const float* __restrict__ bias2,
    const float* __restrict__ bias3,
    const float* __restrict__ bsc, const float* __restrict__ resid,
    int M, int N, int K, long aBatch, long bBatch, long cBatch) {
  __shared__ __align__(16) short SH[65536];   // 128 KiB: A halves then B halves
  auto Ab = [&](int buf, int ks) { return SH + (buf * 2 + ks) * 8192; };
  auto Bb = [&](int buf, int ks) { return SH + 32768 + (buf * 2 + ks) * 8192; };

  // bijective XCD-chunked remap (nwg % 8 == 0 in all our launches)
  const int gx = gridDim.x, gy = gridDim.y;
  const int nwg = gx * gy * gridDim.z;
  int lin = blockIdx.x + gx * (blockIdx.y + gy * blockIdx.z);
  int swz = lin;
  if ((nwg & 7) == 0) {
    const int cpx = nwg >> 3;
    swz = (lin & 7) * cpx + (lin >> 3);
  }
  const int NTN = N >> 8;
  const int NTM = M >> 8;
  const int tid = threadIdx.x;
  const int lane = tid & 63;
  const int wid = tid >> 6;
  const int wm = wid >> 2, wn = wid & 3;

  // per-thread staging invariants (swizzled LDS offset -> (row, col) decode)
  const int o0 = tid * 16, o1 = o0 + 8192;
  const int lo0 = SWZ(o0), lo1 = SWZ(o1);
  const int srow[2] = {lo0 >> 6, lo1 >> 6};
  const int scol[2] = {(lo0 & 63) >> 1, (lo1 & 63) >> 1};

  for (int rep = 0; rep < MREP; ++rep) {
    const int wg = swz + rep * nwg;
    int ntile, mtile, bz;
    if (WALK) {
      mtile = wg % NTM;
      const int rest = wg / NTM;
      ntile = rest % NTN;
      bz = rest / NTN;
    } else {
      ntile = wg % NTN;
      const int rest = wg / NTN;
      mtile = rest % NTM;
      bz = rest / NTM;
    }

    const short* Ag = ASEL ? (A + (long)(bz >> 2) * aBatch) : (A + (long)bz * aBatch);
    const short* Bg = Bt + (long)bz * bBatch;
    const int m0 = mtile << 8, n0 = ntile << 8;

    // per-rep staging base pointers (hoists addr calc + AMIR mirror out of loop)
    const short* bA[2];
    const short* bB[2];
#pragma unroll
    for (int j = 0; j < 2; ++j) {
      if (AMIR) {
        int grow = m0 + srow[j];
        int b_ = grow >> 12, s_ = grow & (S - 1);
        int sm = (s_ <= 2048) ? s_ : (4096 - s_);
        bA[j] = Ag + ((long)b_ * MH + sm) * K + scol[j];
      } else {
        bA[j] = Ag + (long)(m0 + srow[j]) * K + scol[j];
      }
      bB[j] = Bg + (long)(n0 + srow[j]) * K + scol[j];
    }

    f32x4 acc[8][4];
#pragma unroll
    for (int i = 0; i < 8; ++i)
#pragma unroll
      for (int j = 0; j < 4; ++j) acc[i][j] = (f32x4){0.f, 0.f, 0.f, 0.f};

    const int NT = K >> 6;
    auto stage = [&](int h) {
      const int tau = h >> 2, q = h & 3;
      const int ks = q >> 1;
      const long k0 = (long)tau * 64 + ks * 32;
      const int dbase = (q & 1) * 65536 + (((tau & 1) << 1) + ks) * 16384;
      const short* b0 = (q & 1) ? bB[0] : bA[0];
      const short* b1 = (q & 1) ? bB[1] : bA[1];
      GLOAD(b0 + k0, (short*)((char*)SH + dbase + o0));
      GLOAD(b1 + k0, (short*)((char*)SH + dbase + o1));
    };

    if (rep > 0) SBAR();   // previous rep's LDS reads long done; order stage writes
#pragma unroll
    for (int h = 0; h < 7; ++h) stage(h);
    asm volatile("s_waitcnt vmcnt(6)" ::: "memory");
    SBAR();

    short8 bf[4];
    for (int t = 0; t < NT; ++t) {
      const int buf = t & 1;
#pragma unroll
      for (int p = 0; p < 4; ++p) {
        const int ks = p >> 1, mh = p & 1;
        short8 af[4];
        {
          const short* Ah = Ab(buf, ks);
          const int kb = (lane >> 4) * 16;
          const int r0 = wm * 128 + mh * 64 + (lane & 15);
#pragma unroll
          for (int i = 0; i < 4; ++i) {
            int byte = (r0 + i * 16) * 64 + kb;
            byte = SWZ(byte);
            af[i] = *(const short8*)((const char*)Ah + byte);
          }
          if (mh == 0) {
            const short* Bh = Bb(buf, ks);
            const int c0 = wn * 64 + (lane & 15);
#pragma unroll
            for (int j = 0; j < 4; ++j) {
              int byte = (c0 + j * 16) * 64 + kb;
              byte = SWZ(byte);
              bf[j] = *(const short8*)((const char*)Bh + byte);
            }
          }
        }
        { const int h = 4 * t + p + 7; if (h < 4 * NT) stage(h); }
        SBAR();
        WAITL0();
        __builtin_amdgcn_s_setprio(1);
#pragma unroll
        for (int i = 0; i < 4; ++i)
#pragma unroll
          for (int j = 0; j < 4; ++j)
            acc[mh * 4 + i][j] = __builtin_amdgcn_mfma_f32_16x16x32_bf16(
                af[i], bf[j], acc[mh * 4 + i][j], 0, 0, 0);
        __builtin_amdgcn_s_setprio(0);
        if (p == 3) {
          if (t < NT - 2) {
            asm volatile("s_waitcnt vmcnt(6)" ::: "memory");
          } else if (t == NT - 2) {
            asm volatile("s_waitcnt vmcnt(0)" ::: "memory");
          }
        }
        SBAR();
      }
    }

    // epilogue: C/D layout col = lane&15, row = (lane>>4)*4 + reg
    const int rl = (lane >> 4) << 2;
#pragma unroll
    for (int f = 0; f < 8; ++f) {
      const int rbase = m0 + wm * 128 + f * 16 + rl;
#pragma unroll
      for (int j = 0; j < 4; ++j) {
        const int col = n0 + wn * 64 + j * 16 + (lane & 15);
        f32x4 a = acc[f][j];
        if constexpr (EPI == 0) {
          short* cp = Cb + (long)bz * cBatch;
#pragma unroll
          for (int r = 0; r < 4; ++r)
            cp[(long)(rbase + r) * N + col] = (short)f2bf(a[r]);
        } else if constexpr (EPI == 4) {
          const int pidx = col >> 10;
          const int dcol = col & (DM - 1);
          short* Cp = (pidx == 0) ? Cb : ((pidx == 1) ? Cb2 : Cb3);
          const float* bp = (pidx == 0) ? bias : ((pidx == 1) ? bias2 : bias3);
          const float bi = bp[dcol] * (bsc ? bsc[0] : 1.f);
#pragma unroll
          for (int r = 0; r < 4; ++r)
            Cp[(long)(rbase + r) * DM + dcol] = (short)f2bf(a[r] + bi);
        } else {
          float bi = bias[col];
#pragma unroll
          for (int r = 0; r < 4; ++r) {
            long o = (long)(rbase + r) * N + col;
            Cf[o] = a[r] + bi + resid[o];
          }
        }
      }
    }
  }
}

// ---------------- launch ----------------
extern "C" void kernel_launch(void* const* d_in, const int* in_sizes, int n_in,
                              void* d_out, int out_size, void* d_ws, size_t ws_size,
                              hipStream_t stream) {
  const float* x     = (const float*)d_in[0];
  const float* fd    = (const float*)d_in[1];
  const float* Wq    = (const float*)d_in[2];
  const float* bq    = (const float*)d_in[3];
  const float* Wk    = (const float*)d_in[4];
  const float* bk    = (const float*)d_in[5];
  const float* Wv    = (const float*)d_in[6];
  const float* bv    = (const float*)d_in[7];
  const float* Wo    = (const float*)d_in[8];
  const float* bo    = (const float*)d_in[9];
  const float* alpha = (const float*)d_in[10];
  const float* fsc   = (const float*)d_in[11];
  float* out = (float*)d_out;

  // --- workspace layout (~112 MB) ---
  char* wp = (char*)d_ws;
  auto alloc = [&](size_t bytes) {
    char* p = wp;
    wp += (bytes + 255) & ~(size_t)255;
    return p;
  };
  float* cos_tab = (float*)alloc(S * 4);
  float* c_arr   = (float*)alloc(S * 4);          // c_arr[0] = c0 bias factor
  float* g       = (float*)alloc(S * 4);
  float* wsm     = (float*)alloc((size_t)NB * NH * S * 4);   // 1 MB
  short* WTcat = (short*)alloc((size_t)4 * DM * DM * 2);  // Wq,Wk,Wv,Wo transposed
  short* WoT   = WTcat + (size_t)3 * DM * DM;
  short* slotA = (short*)alloc((size_t)NB * DS * 2);  // ABout -> V
  short* slotB = (short*)alloc((size_t)NB * DS * 2);  // Ge/Go -> Mc2 + A2t
  short* slotC = (short*)alloc((size_t)NB * DS * 2);  // Xs -> att_half

  // d_out scratch phases: uv (34.6MB) during G-phase; Q,K during attention
  short* uv = (short*)d_out;                        // [8][DM][KH2]
  short* Qn = (short*)d_out;                        // [(b,s)][DM] 33.5 MB
  short* Kn = (short*)d_out + (size_t)NB * DS;      // [(b,s)][DM] 33.5 MB

  short* Ge  = slotB;                               // [2][MEO][KH2] (Ge,Go)
  short* ABout = slotA;                             // [8][MEO][DM]
  short* Xs  = slotC;
  short* Vn  = slotA;                               // V natural (after ABout dead)
  short* Mc2 = slotB;                               // 9.73 MB (after Ge dead)
  short* A2t = (short*)((char*)slotB + 10u * 1024 * 1024);
  short* att_half = slotC;

  dim3 blk(256), blk8(512);

  // 1) tables + g  2) even/odd matrices  3) fold x + weight transposes
  k_tabg<<<dim3(16 + S / 16), blk, 0, stream>>>(fd, alpha, fsc, cos_tab, c_arr, g);
  k_buildEO<<<dim3((unsigned)((long)MEO * KH2 / 8 / 256)), blk, 0, stream>>>(g, Ge);
  k_prep<<<dim3(49, 16, NB), blk, 0, stream>>>(x, uv, Wq, Wk, Wv, Wo, WTcat);

  // 4) even/odd spectral GEMM: AB[z] = (z<4 ? Ge : Go) @ uv[z]; 256 wg
  dim3 geo(DM / 256, MEO / 256, 8);
  gemm8<0, 0, 1><<<geo, blk8, 0, stream>>>(Ge, uv, ABout, nullptr, nullptr, nullptr,
                                           nullptr, nullptr, nullptr, nullptr, nullptr,
                                           MEO, DM, KH2,
                                           (long)MEO * KH2, (long)DM * KH2, (long)MEO * DM);
  // 5) unfold mirror + row n=2048 into Xs [b][s][d]
  k_unfold2<<<dim3(8192), blk, 0, stream>>>(ABout, g, uv, Xs);

  // 6) fused q/k/v projections (EPI=4, persistent 256 blocks x 3 tiles)
  gemm8<4, 0, 0, 0, 3><<<dim3(256), blk8, 0, stream>>>(
      Xs, WTcat, Qn, Kn, Vn, nullptr, bq, bk, bv, c_arr, nullptr,
      MTOT, 3 * DM, DM, 0, 0, 0);

  // 7) fused logits + head-softmax   8) attend+fold + buildM2 (merged)
  k_logsoft<<<dim3(MTOT / 16), blk, 0, stream>>>(Qn, Kn, wsm);
  k_attfoldM2<<<dim3(33 + 38, DM / 64, NB), blk, 0, stream>>>(Vn, wsm, A2t, cos_tab, Mc2);

  // 9) att_time_half = Mc2 @ A2
  dim3 ghalf(DM / 256, MH / 256, NB);
  gemm8<0><<<ghalf, blk8, 0, stream>>>(Mc2, A2t, att_half, nullptr, nullptr, nullptr,
                                       nullptr, nullptr, nullptr, nullptr, nullptr,
                                       MH, DM, KH, 0, (long)DM * KH, (long)MH * DM);

  // 10) out = att_time @ Wo + bo + x  (A rows via mirror; fp32 epilogue)
  dim3 gproj(DM / 256, MTOT / 256, 1);
  gemm8<2, 1><<<gproj, blk8, 0, stream>>>(att_half, WoT, nullptr, nullptr, nullptr, out,
                                          bo, nullptr, nullptr, nullptr, x,
                                          MTOT, DM, DM, 0, 0, 0);
}